// Round 4
// baseline (357.063 us; speedup 1.0000x reference)
//
#include <hip/hip_runtime.h>
#include <hip/hip_bf16.h>
#include <stdint.h>
#include <math.h>

// ---------------------------------------------------------------------------
// HMC hierarchical classifier (B=8192, F=1024, H=2048, L1N=64, L2N=256).
// f32-accurate GEMMs via 2-plane f16 split (Ootomo): v = vh + vl*2^-11,
// 3 MFMAs / 2 accumulators, dropped ll ~ 2^-22 rel.
// R14: address hoisting.  R13 post-mortem: VALUBusy 24% ~= 800cyc/slot of
// recomputed ds/global addresses (SB0 pins blocked hoisting).  The swizzle
// term (row>>1)&3 == (ml>>1)&3 for ALL reads (row contributions are 0 mod 4
// after >>1), so each wave's whole read set = one base VGPR per ring slot
// + a 16-bit ds imm.  h1: 6 ds-base VGPRs (A,B x ring-3); h2: 8 (ring-4).
// Gloads: persistent byte-pointers advanced +64/slot.  Ring unrolled so all
// buffer bases are compile-time.  Schedule/lgkm counts byte-identical R13.
// prep_all / head_fused / l2_softmax unchanged.
// ---------------------------------------------------------------------------

typedef _Float16 f16x8 __attribute__((ext_vector_type(8)));
typedef float    f32x4 __attribute__((ext_vector_type(4)));

#define MASK_VALUE (-10000.0f)
#define SWZ(r) ((((r) + ((r) >> 2))) & 3)          // legacy swizzle (head_fused)
#define RSCALE 2048.0f
#define INV_RSCALE (1.0f / 2048.0f)

#define GLOBAL_AS __attribute__((address_space(1)))
#define LDS_AS    __attribute__((address_space(3)))

__device__ __forceinline__ void gload16(const void* g, void* lds) {
    __builtin_amdgcn_global_load_lds((const GLOBAL_AS void*)g, (LDS_AS void*)lds, 16, 0, 0);
}

__device__ __forceinline__ float rd_any(const void* p, size_t i, int flag) {
    return flag ? (float)((const __hip_bfloat16*)p)[i] : ((const float*)p)[i];
}

__device__ __forceinline__ void wg_bar() {
    asm volatile("" ::: "memory");
    __builtin_amdgcn_s_barrier();
    asm volatile("" ::: "memory");
}
#define LGKMN(n) do { asm volatile("s_waitcnt lgkmcnt(" #n ")" ::: "memory"); \
                      __builtin_amdgcn_sched_barrier(0); } while (0)
#define VMW(n)  asm volatile("s_waitcnt vmcnt(" #n ")" ::: "memory")
#define SB0()   __builtin_amdgcn_sched_barrier(0)
#define MFMA16(a,b,c) __builtin_amdgcn_mfma_f32_16x16x32_f16((a),(b),(c),0,0,0)

// ---------------------------------------------------------------------------
__global__ void detect_dtype(const unsigned int* __restrict__ x, int* __restrict__ flag) {
    __shared__ int cnt;
    if (threadIdx.x == 0) cnt = 0;
    __syncthreads();
    int local = 0;
#pragma unroll
    for (int i = 0; i < 4; ++i) {
        unsigned int w = x[threadIdx.x * 4 + i];
        unsigned int e = (w >> 7) & 0xFFu;
        if (e >= 96u && e <= 144u) local++;
    }
    atomicAdd(&cnt, local);
    __syncthreads();
    if (threadIdx.x == 0) *flag = (cnt >= 600) ? 1 : 0;   // 1 = bf16 inputs
}

// ---------------------------------------------------------------------------
// prep_all: fused prep.  Sections (by blockIdx.x):
//   [0,8192)      split_x        (x -> xh, xl)
//   [8192,8704)   split_w1t      (W1_1 -> whT, wlT)   32x16 tiles
//   [8704,9216)   transpose W2_1 -> W2Tf  [2048][1024] 32x16 tiles
//   [9216,9472)   transpose W2_2 -> W22Tf [256][4096]   4x64 tiles
//   [9472,9504)   split_w12t     (W1_2 -> w12h, w12l)  32 tiles
// ---------------------------------------------------------------------------
__global__ void prep_all(
    const void* __restrict__ x, const void* __restrict__ W1_1,
    const void* __restrict__ W2_1, const void* __restrict__ W2_2,
    const void* __restrict__ W1_2,
    _Float16* __restrict__ xh, _Float16* __restrict__ xl,
    _Float16* __restrict__ whT, _Float16* __restrict__ wlT,
    _Float16* __restrict__ W2Tf, _Float16* __restrict__ W22Tf,
    _Float16* __restrict__ w12h, _Float16* __restrict__ w12l,
    const int* __restrict__ flagp)
{
    __shared__ __align__(16) float tile[64][65];
    int flag = *flagp;
    int bid = blockIdx.x, t = threadIdx.x;
    int tx = t & 63, ty = t >> 6;

    if (bid < 8192) {
        size_t i = ((size_t)bid * 256 + t) * 4;
#pragma unroll
        for (int j = 0; j < 4; ++j) {
            float a = rd_any(x, i + j, flag);
            _Float16 h = (_Float16)a;
            xh[i + j] = h;
            xl[i + j] = (_Float16)((a - (float)h) * RSCALE);
        }
        return;
    }

    if (bid < 8704) {                       // split_w1t: [1024][2048] -> T
        int b = bid - 8192;
        int c0 = (b & 31) * 64, r0 = (b >> 5) * 64;
#pragma unroll
        for (int i = 0; i < 16; ++i) {
            int r = ty + i * 4;
            tile[r][tx] = rd_any(W1_1, (size_t)(r0 + r) * 2048 + c0 + tx, flag);
        }
        __syncthreads();
#pragma unroll
        for (int i = 0; i < 16; ++i) {
            int r = ty + i * 4;
            size_t o = (size_t)(c0 + r) * 1024 + r0 + tx;
            float a = tile[tx][r];
            _Float16 h = (_Float16)a;
            whT[o] = h;
            wlT[o] = (_Float16)((a - (float)h) * RSCALE);
        }
        return;
    }

    if (bid < 9216) {                       // W2_1 [1024][2048] -> W2Tf
        int b = bid - 8704;
        int c0 = (b & 31) * 64, r0 = (b >> 5) * 64;
#pragma unroll
        for (int i = 0; i < 16; ++i) {
            int r = ty + i * 4;
            tile[r][tx] = rd_any(W2_1, (size_t)(r0 + r) * 2048 + c0 + tx, flag);
        }
        __syncthreads();
#pragma unroll
        for (int i = 0; i < 16; ++i) {
            int r = ty + i * 4;
            W2Tf[(size_t)(c0 + r) * 1024 + r0 + tx] = (_Float16)tile[tx][r];
        }
        return;
    }

    if (bid < 9472) {                       // W2_2 [4096][256] -> W22Tf
        int b = bid - 9216;
        int c0 = (b & 3) * 64, r0 = (b >> 2) * 64;
#pragma unroll
        for (int i = 0; i < 16; ++i) {
            int r = ty + i * 4;
            tile[r][tx] = rd_any(W2_2, (size_t)(r0 + r) * 256 + c0 + tx, flag);
        }
        __syncthreads();
#pragma unroll
        for (int i = 0; i < 16; ++i) {
            int r = ty + i * 4;
            W22Tf[(size_t)(c0 + r) * 4096 + r0 + tx] = (_Float16)tile[tx][r];
        }
        return;
    }

    {                                       // split_w12t: [2048][64] -> T
        int b = bid - 9472;
        int r0 = b * 64;
#pragma unroll
        for (int i = 0; i < 16; ++i) {
            int r = ty + i * 4;
            tile[r][tx] = rd_any(W1_2, (size_t)(r0 + r) * 64 + tx, flag);
        }
        __syncthreads();
#pragma unroll
        for (int i = 0; i < 16; ++i) {
            int r = ty + i * 4;
            size_t o = (size_t)r * 2048 + r0 + tx;
            float a = tile[tx][r];
            _Float16 h = (_Float16)a;
            w12h[o] = h;
            w12l[o] = (_Float16)((a - (float)h) * RSCALE);
        }
    }
}

// ---------------------------------------------------------------------------
// h12_gemm8: R13 skewed slot-ring schedule + hoisted addressing.
//   ds_read addr = base VGPR (per ring slot) + 16-bit imm (rt/ct/plane).
//   gload addr = persistent byte pointers, += 64 per slot.
//   Ring unrolled: all LDS buffer bases compile-time constants.
// ---------------------------------------------------------------------------
__global__ __launch_bounds__(512, 2) void h12_gemm8(
    const _Float16* __restrict__ xh, const _Float16* __restrict__ xl,
    const _Float16* __restrict__ whT, const _Float16* __restrict__ wlT,
    const void* __restrict__ b11,
    const _Float16* __restrict__ W2Tf, const void* __restrict__ b21,
    _Float16* __restrict__ h1h, _Float16* __restrict__ h1l,
    _Float16* __restrict__ h2b,
    const int* __restrict__ flagp)
{
    __shared__ __align__(16) char smem[147456];
    int flag = *flagp;
    int t = threadIdx.x, w = t >> 6, lane = t & 63;
    int ml = lane & 15, q = lane >> 4, rq = q * 4;
    int t16 = t * 16;
    int swz16 = (q ^ ((ml >> 1) & 3)) << 4;            // swizzle: invariant per lane
    int r0g = t >> 2;                                   // staging row within half-tile
    int c0g = (t & 3) ^ ((t >> 3) & 3);                 // staging swizzled chunk

    int xcd = blockIdx.x & 7, rblk = blockIdx.x >> 3;   // 8 XCDs x 96

    if (rblk < 64) {
        // ================= h1: 3-term, BM=256 BN=128, ring-3 =================
        int lb = xcd * 64 + rblk;
        int mt = lb >> 4, nt = lb & 15;
        int i0 = mt * 256, j0 = nt * 128;
        int wr = w & 3, wc = w >> 2;                    // 4 x 2 waves

        f32x4 acc1[4][4], acc2[4][4];
#pragma unroll
        for (int a = 0; a < 4; ++a)
#pragma unroll
            for (int b = 0; b < 4; ++b) {
                acc1[a][b] = (f32x4){0.f, 0.f, 0.f, 0.f};
                acc2[a][b] = (f32x4){0.f, 0.f, 0.f, 0.f};
            }

        // persistent frag regs
        f16x8 ah[4], al[4], bAh[2], bAl[2], bBh[2], bBl[2];

        // ds base addrs (per ring slot); imm covers rt/ct*1024 + plane offset
        int aA0 = (wr * 64 + ml) * 64 + swz16;
        int aA1 = aA0 + 49152, aA2 = aA0 + 98304;
        int aB0 = 32768 + (wc * 64 + ml) * 64 + swz16;
        int aB1 = aB0 + 49152, aB2 = aB0 + 98304;

        // global staging pointers (byte), advanced +64 per slot
        const char* pxh = (const char*)xh + (size_t)(i0 + r0g) * 2048 + c0g * 16;
        const char* pxl = (const char*)xl + (size_t)(i0 + r0g) * 2048 + c0g * 16;
        const char* pwh = (const char*)whT + (size_t)(j0 + r0g) * 2048 + c0g * 16;
        const char* pwl = (const char*)wlT + (size_t)(j0 + r0g) * 2048 + c0g * 16;

        auto stage6 = [&](int pfB) {
            gload16(pxh,          smem + pfB +         t16);
            gload16(pxh + 262144, smem + pfB +  8192 + t16);
            gload16(pxl,          smem + pfB + 16384 + t16);
            gload16(pxl + 262144, smem + pfB + 24576 + t16);
            gload16(pwh,          smem + pfB + 32768 + t16);
            gload16(pwl,          smem + pfB + 40960 + t16);
            pxh += 64; pxl += 64; pwh += 64; pwl += 64;
        };
        auto rdBA = [&](int aB) {                       // 4 reads: B ct0,1
            bAh[0] = *(const f16x8*)(smem + aB);
            bAh[1] = *(const f16x8*)(smem + aB + 1024);
            bAl[0] = *(const f16x8*)(smem + aB + 8192);
            bAl[1] = *(const f16x8*)(smem + aB + 9216);
        };
        auto rdA = [&](int aA) {                        // 8 reads: A planes
            ah[0] = *(const f16x8*)(smem + aA);
            ah[1] = *(const f16x8*)(smem + aA + 1024);
            ah[2] = *(const f16x8*)(smem + aA + 2048);
            ah[3] = *(const f16x8*)(smem + aA + 3072);
            al[0] = *(const f16x8*)(smem + aA + 16384);
            al[1] = *(const f16x8*)(smem + aA + 17408);
            al[2] = *(const f16x8*)(smem + aA + 18432);
            al[3] = *(const f16x8*)(smem + aA + 19456);
        };
        auto rdBB = [&](int aB) {                       // 4 reads: B ct2,3
            bBh[0] = *(const f16x8*)(smem + aB + 2048);
            bBh[1] = *(const f16x8*)(smem + aB + 3072);
            bBl[0] = *(const f16x8*)(smem + aB + 10240);
            bBl[1] = *(const f16x8*)(smem + aB + 11264);
        };

        auto h1slot = [&](int aAn, int aBn, int pfB, bool st, bool rd) {
            if (st) stage6(pfB);
            LGKMN(4);                                   // bA, ah/al ready
            __builtin_amdgcn_s_setprio(1);
#pragma unroll
            for (int rt = 0; rt < 4; ++rt)
#pragma unroll
                for (int ct = 0; ct < 2; ++ct) {
                    acc1[rt][ct] = MFMA16(ah[rt], bAh[ct], acc1[rt][ct]);
                    acc2[rt][ct] = MFMA16(ah[rt], bAl[ct], acc2[rt][ct]);
                    acc2[rt][ct] = MFMA16(al[rt], bAh[ct], acc2[rt][ct]);
                }
            __builtin_amdgcn_s_setprio(0);
            LGKMN(0);                                   // bB ready
            if (st) { VMW(6); } else { VMW(0); }        // next slot's LDS landed
            wg_bar();
            if (rd) rdBA(aBn);
            SB0();
            __builtin_amdgcn_s_setprio(1);
#pragma unroll
            for (int rt = 0; rt < 4; ++rt)
#pragma unroll
                for (int ct = 0; ct < 2; ++ct) {
                    acc1[rt][ct + 2] = MFMA16(ah[rt], bBh[ct], acc1[rt][ct + 2]);
                    acc2[rt][ct + 2] = MFMA16(ah[rt], bBl[ct], acc2[rt][ct + 2]);
                    acc2[rt][ct + 2] = MFMA16(al[rt], bBh[ct], acc2[rt][ct + 2]);
                }
            __builtin_amdgcn_s_setprio(0);
            if (rd) { rdA(aAn); SB0(); rdBB(aBn); }
            SB0();
        };

        // prologue: stage slots 0,1; issue slot-0 reads in invariant order
        stage6(0);
        stage6(49152);
        VMW(6);                                         // slot0 landed
        wg_bar();
        rdBA(aB0); SB0();
        rdA(aA0);  SB0();
        rdBB(aB0); SB0();

        for (int tr = 0; tr < 10; ++tr) {               // slots 0..29
            h1slot(aA1, aB1, 98304, true, true);        // cur=0, pf=2
            h1slot(aA2, aB2, 0,     true, true);        // cur=1, pf=0
            h1slot(aA0, aB0, 49152, true, true);        // cur=2, pf=1
        }
        h1slot(aA1, aB1, 0, false, true);               // s=30 (cur=0)
        h1slot(aA2, aB2, 0, false, false);              // s=31 (cur=1)

        // ---- epilogue: bias + relu, 2-plane split out via LDS restage ----
#pragma unroll
        for (int ct = 0; ct < 4; ++ct) {
            float bv = rd_any(b11, j0 + wc * 64 + ct * 16 + ml, flag);
#pragma unroll
            for (int rt = 0; rt < 4; ++rt)
#pragma unroll
                for (int rr = 0; rr < 4; ++rr) {
                    float v = acc1[rt][ct][rr] + acc2[rt][ct][rr] * INV_RSCALE + bv;
                    acc1[rt][ct][rr] = v > 0.f ? v : 0.f;
                }
        }
        _Float16* C = (_Float16*)smem;
#pragma unroll
        for (int p = 0; p < 2; ++p) {
            __syncthreads();
#pragma unroll
            for (int rt = 0; rt < 4; ++rt)
#pragma unroll
                for (int ct = 0; ct < 4; ++ct)
#pragma unroll
                    for (int rr = 0; rr < 4; ++rr) {
                        float v = acc1[rt][ct][rr];
                        _Float16 h = (_Float16)v;
                        _Float16 outv = (p == 0) ? h
                                      : (_Float16)((v - (float)h) * RSCALE);
                        int rl = wr * 64 + rt * 16 + rq + rr;
                        int cl = wc * 64 + ct * 16 + ml;
                        C[rl * 136 + cl] = outv;
                    }
            __syncthreads();
            _Float16* dst = (p == 0) ? h1h : h1l;
#pragma unroll
            for (int i = 0; i < 8; ++i) {
                int c = i * 512 + t;
                int row = c >> 4, c8 = (c & 15) * 8;
                *(f16x8*)(dst + (size_t)(i0 + row) * 2048 + j0 + c8) =
                    *(const f16x8*)(C + row * 136 + c8);
            }
        }
    } else {
        // ================= h2: 1-term, BM=256 BN=256, ring-4 =================
        int lb = xcd * 32 + (rblk - 64);
        int mt = lb >> 3, nt = lb & 7;
        int i0 = mt * 256, j0 = nt * 256;
        int wr = w & 1, wc = w >> 1;                    // 2 x 4 waves

        f32x4 acc[8][4];
#pragma unroll
        for (int a = 0; a < 8; ++a)
#pragma unroll
            for (int b = 0; b < 4; ++b) acc[a][b] = (f32x4){0.f, 0.f, 0.f, 0.f};

        // persistent frags: af rt0-3, af rt4-7, bf double-buffer
        f16x8 af0[4], af4[4], bfa[4], bfb[4];

        // ds base addrs per ring slot (A @0, B @16384 within 32KiB slot)
        int aA_0 = (wr * 128 + ml) * 64 + swz16;
        int aA_1 = aA_0 + 32768, aA_2 = aA_0 + 65536, aA_3 = aA_0 + 98304;
        int aB_0 = 16384 + (wc * 64 + ml) * 64 + swz16;
        int aB_1 = aB_0 + 32768, aB_2 = aB_0 + 65536, aB_3 = aB_0 + 98304;

        const char* pxh2 = (const char*)xh + (size_t)(i0 + r0g) * 2048 + c0g * 16;
        const char* pw2  = (const char*)W2Tf + (size_t)(j0 + r0g) * 2048 + c0g * 16;

        auto stage4 = [&](int pfB) {
            gload16(pxh2,          smem + pfB +         t16);
            gload16(pxh2 + 262144, smem + pfB +  8192 + t16);
            gload16(pw2,           smem + pfB + 16384 + t16);
            gload16(pw2 + 262144,  smem + pfB + 24576 + t16);
            pxh2 += 64; pw2 += 64;
        };
        auto rdBF = [&](int aB, f16x8* dst) {           // 4 reads: all B ct
            dst[0] = *(const f16x8*)(smem + aB);
            dst[1] = *(const f16x8*)(smem + aB + 1024);
            dst[2] = *(const f16x8*)(smem + aB + 2048);
            dst[3] = *(const f16x8*)(smem + aB + 3072);
        };
        auto rdA0 = [&](int aA) {                       // 4 reads: rt0-3
            af0[0] = *(const f16x8*)(smem + aA);
            af0[1] = *(const f16x8*)(smem + aA + 1024);
            af0[2] = *(const f16x8*)(smem + aA + 2048);
            af0[3] = *(const f16x8*)(smem + aA + 3072);
        };
        auto rdA4 = [&](int aA) {                       // 4 reads: rt4-7
            af4[0] = *(const f16x8*)(smem + aA + 4096);
            af4[1] = *(const f16x8*)(smem + aA + 5120);
            af4[2] = *(const f16x8*)(smem + aA + 6144);
            af4[3] = *(const f16x8*)(smem + aA + 7168);
        };

        auto h2slot = [&](int aAn, int aBn, int pfB, bool st, bool rd,
                          f16x8* BFC, f16x8* BFN) {
            if (st) stage4(pfB);
            LGKMN(4);                                   // BFC, af0 ready
            __builtin_amdgcn_s_setprio(1);
#pragma unroll
            for (int rt = 0; rt < 4; ++rt)
#pragma unroll
                for (int ct = 0; ct < 4; ++ct)
                    acc[rt][ct] = MFMA16(af0[rt], BFC[ct], acc[rt][ct]);
            __builtin_amdgcn_s_setprio(0);
            LGKMN(0);                                   // af4 ready
            if (st) { VMW(4); } else { VMW(0); }
            wg_bar();
            if (rd) { rdBF(aBn, BFN); rdA0(aAn); }
            SB0();
            __builtin_amdgcn_s_setprio(1);
#pragma unroll
            for (int rt = 0; rt < 4; ++rt)
#pragma unroll
                for (int ct = 0; ct < 4; ++ct)
                    acc[rt + 4][ct] = MFMA16(af4[rt], BFC[ct], acc[rt + 4][ct]);
            __builtin_amdgcn_s_setprio(0);
            if (rd) rdA4(aAn);
            SB0();
        };

        // prologue
        stage4(0);
        stage4(32768);
        VMW(4);
        wg_bar();
        rdBF(aB_0, bfa); SB0();
        rdA0(aA_0);      SB0();
        rdA4(aA_0);      SB0();

        for (int qd = 0; qd < 7; ++qd) {                // slots 0..27
            h2slot(aA_1, aB_1, 65536, true, true,  bfa, bfb);  // cur=0, pf=2
            h2slot(aA_2, aB_2, 98304, true, true,  bfb, bfa);  // cur=1, pf=3
            h2slot(aA_3, aB_3, 0,     true, true,  bfa, bfb);  // cur=2, pf=0
            h2slot(aA_0, aB_0, 32768, true, true,  bfb, bfa);  // cur=3, pf=1
        }
        h2slot(aA_1, aB_1, 65536, true,  true,  bfa, bfb);     // s=28
        h2slot(aA_2, aB_2, 98304, true,  true,  bfb, bfa);     // s=29
        h2slot(aA_3, aB_3, 0,     false, true,  bfa, bfb);     // s=30
        h2slot(aA_0, aB_0, 0,     false, false, bfb, bfa);     // s=31

        // ---- epilogue: bias + relu, f16 out via LDS restage ----
        _Float16* C = (_Float16*)smem;
        __syncthreads();
#pragma unroll
        for (int ct = 0; ct < 4; ++ct) {
            float bv = rd_any(b21, j0 + wc * 64 + ct * 16 + ml, flag);
#pragma unroll
            for (int rt = 0; rt < 8; ++rt)
#pragma unroll
                for (int rr = 0; rr < 4; ++rr) {
                    float v = acc[rt][ct][rr] + bv;
                    v = v > 0.f ? v : 0.f;
                    int rl = wr * 128 + rt * 16 + rq + rr;
                    int cl = wc * 64 + ct * 16 + ml;
                    C[rl * 264 + cl] = (_Float16)v;
                }
        }
        __syncthreads();
#pragma unroll
        for (int i = 0; i < 16; ++i) {
            int c = i * 512 + t;
            int row = c >> 5, c8 = (c & 31) * 8;
            *(f16x8*)(h2b + (size_t)(i0 + row) * 2048 + j0 + c8) =
                *(const f16x8*)(C + row * 264 + c8);
        }
    }
}

// ---------------------------------------------------------------------------
// head_fused: blocks [0,512) = l2_gemm (partials); [512,1024) = l1_mfma
// (L1 softmax + argmax).  Both read only h-planes; independent.
// ---------------------------------------------------------------------------
__global__ __launch_bounds__(256, 2) void head_fused(
    const _Float16* __restrict__ h1h, const _Float16* __restrict__ h1l,
    const _Float16* __restrict__ h2b, const _Float16* __restrict__ W22T,
    float* __restrict__ partials,
    const _Float16* __restrict__ w12h, const _Float16* __restrict__ w12l,
    const void* __restrict__ b12, float* __restrict__ L1out,
    int* __restrict__ parent, const int* __restrict__ flagp)
{
    constexpr int BK = 32;
    __shared__ __align__(16) char smem[16384];
    int flag = *flagp;
    int t = threadIdx.x, w = t >> 6, lane = t & 63;
    int ml = lane & 15, q = lane >> 4;

    if (blockIdx.x < 512) {
        // ----- l2_gemm -----
        _Float16* As = (_Float16*)smem;
        _Float16* Bs = (_Float16*)(smem + 8192);
        int bid = blockIdx.x;
        int g = bid & 7, s = bid >> 3;
        int mt = g * 8 + (s & 7);
        int rest = s >> 3;
        int nt = rest & 1, kc = rest >> 1;
        int i0 = mt * 128, j0 = nt * 128;
        const _Float16* Abase = (kc < 2) ? h1h : h2b;
        int kof = (kc & 1) * 1024;
        int wr = w & 1, wcb = w >> 1;

        f32x4 acc[4][4];
#pragma unroll
        for (int a = 0; a < 4; ++a)
#pragma unroll
            for (int b = 0; b < 4; ++b) acc[a][b] = (f32x4){0.f, 0.f, 0.f, 0.f};

        for (int kt = 0; kt < 1024; kt += BK) {
            __syncthreads();
#pragma unroll
            for (int qq = 0; qq < 2; ++qq) {
                int c = qq * 256 + t;
                int row = c >> 2;
                int gc = (c & 3) ^ SWZ(row);
                gload16(Abase + (size_t)(i0 + row) * 2048 + kof + kt + gc * 8, (char*)As + c * 16);
                gload16(W22T + (size_t)(j0 + row) * 4096 + kc * 1024 + kt + gc * 8, (char*)Bs + c * 16);
            }
            __syncthreads();
            f16x8 af[4], bf[4];
#pragma unroll
            for (int rt = 0; rt < 4; ++rt) {
                int row = wr * 64 + rt * 16 + ml;
                af[rt] = *(const f16x8*)(As + row * 32 + ((q ^ SWZ(row)) << 3));
            }
#pragma unroll
            for (int ct = 0; ct < 4; ++ct) {
                int row = wcb * 64 + ct * 16 + ml;
                bf[ct] = *(const f16x8*)(Bs + row * 32 + ((q ^ SWZ(row)) << 3));
            }
#pragma unroll
            for (int rt = 0; rt < 4; ++rt)
#pragma unroll
                for (int ct = 0; ct < 4; ++ct)
                    acc[rt][ct] = __builtin_amdgcn_mfma_f32_16x16x32_f16(
                        af[rt], bf[ct], acc[rt][ct], 0, 0, 0);
        }

        float* out = partials + (size_t)kc * 8192 * 256;
        int rq = (lane >> 4) * 4;
#pragma unroll
        for (int ct = 0; ct < 4; ++ct) {
            int nl = j0 + wcb * 64 + ct * 16 + ml;
#pragma unroll
            for (int rt = 0; rt < 4; ++rt) {
                int mbase = i0 + wr * 64 + rt * 16 + rq;
#pragma unroll
                for (int r = 0; r < 4; ++r)
                    out[(size_t)(mbase + r) * 256 + nl] = acc[rt][ct][r];
            }
        }
    } else {
        // ----- l1_mfma: 16 rows/block, 4-wave K-split, 3-term -----
        float* red = (float*)smem;          // [3][4][256] floats = 12 KB
        int r0 = (blockIdx.x - 512) * 16;
        int kq = (lane >> 4) * 8;

        f32x4 acch[4], accx[4];
#pragma unroll
        for (int ct = 0; ct < 4; ++ct) {
            acch[ct] = (f32x4){0.f, 0.f, 0.f, 0.f};
            accx[ct] = (f32x4){0.f, 0.f, 0.f, 0.f};
        }

        size_t aoff = (size_t)(r0 + ml) * 2048 + w * 512 + kq;
        const _Float16* Ah = h1h + aoff;
        const _Float16* Al = h1l + aoff;
        size_t boff[4];
#pragma unroll
        for (int ct = 0; ct < 4; ++ct)
            boff[ct] = (size_t)(ct * 16 + ml) * 2048 + w * 512 + kq;

        f16x8 ah = *(const f16x8*)(Ah), al = *(const f16x8*)(Al);
        f16x8 bh[4], bl[4];
#pragma unroll
        for (int ct = 0; ct < 4; ++ct) {
            bh[ct] = *(const f16x8*)(w12h + boff[ct]);
            bl[ct] = *(const f16x8*)(w12l + boff[ct]);
        }

        for (int kt = 0; kt < 512; kt += 32) {
            int nk = (kt + 32) & 511;
            f16x8 nah = *(const f16x8*)(Ah + nk);
            f16x8 nal = *(const f16x8*)(Al + nk);
            f16x8 nbh[4], nbl[4];
#pragma unroll
            for (int ct = 0; ct < 4; ++ct) {
                nbh[ct] = *(const f16x8*)(w12h + boff[ct] + nk);
                nbl[ct] = *(const f16x8*)(w12l + boff[ct] + nk);
            }
#pragma unroll
            for (int ct = 0; ct < 4; ++ct) {
                acch[ct] = __builtin_amdgcn_mfma_f32_16x16x32_f16(ah, bh[ct], acch[ct], 0, 0, 0);
                accx[ct] = __builtin_amdgcn_mfma_f32_16x16x32_f16(ah, bl[ct], accx[ct], 0, 0, 0);
                accx[ct] = __builtin_amdgcn_mfma_f32_16x16x32_f16(al, bh[ct], accx[ct], 0, 0, 0);
            }
            ah = nah; al = nal;
#pragma unroll
            for (int ct = 0; ct < 4; ++ct) { bh[ct] = nbh[ct]; bl[ct] = nbl[ct]; }
        }

        f32x4 acc[4];
#pragma unroll
        for (int ct = 0; ct < 4; ++ct)
#pragma unroll
            for (int i = 0; i < 4; ++i)
                acc[ct][i] = acch[ct][i] + accx[ct][i] * INV_RSCALE;

        if (w > 0) {
#pragma unroll
            for (int ct = 0; ct < 4; ++ct)
#pragma unroll
                for (int i = 0; i < 4; ++i)
                    red[((w - 1) * 4 + ct) * 256 + lane * 4 + i] = acc[ct][i];
        }
        __syncthreads();
        if (w != 0) return;

#pragma unroll
        for (int wv = 0; wv < 3; ++wv)
#pragma unroll
            for (int ct = 0; ct < 4; ++ct)
#pragma unroll
                for (int i = 0; i < 4; ++i)
                    acc[ct][i] += red[(wv * 4 + ct) * 256 + lane * 4 + i];

        int rq = (lane >> 4) * 4;
        float vals[4][4];
        float vmax[4] = {-1e30f, -1e30f, -1e30f, -1e30f};
        int vidx[4] = {1 << 30, 1 << 30, 1 << 30, 1 << 30};
#pragma unroll
        for (int ct = 0; ct < 4; ++ct) {
            int col = ct * 16 + ml;
            float bv = rd_any(b12, col, flag);
#pragma unroll
            for (int r = 0; r < 4; ++r) {
                float v = acc[ct][r] + bv;
                v = v > 0.f ? v : 0.f;
                vals[ct][r] = v;
                if (v > vmax[r] || (v == vmax[r] && col < vidx[r])) { vmax[r] = v; vidx[r] = col; }
            }
        }
#pragma unroll
        for (int d = 1; d < 16; d <<= 1) {
#pragma unroll
            for (int r = 0; r < 4; ++r) {
                float om = __shfl_xor(vmax[r], d);
                int oi = __shfl_xor(vidx[r], d);
                if (om > vmax[r] || (om == vmax[r] && oi < vidx[r])) { vmax[r] = om; vidx[r] = oi; }
            }
        }
        float vsum[4] = {0.f, 0.f, 0.f, 0.f};
#pragma unroll
        for (int ct = 0; ct < 4; ++ct)
#pragma unroll
            for (int r = 0; r < 4; ++r) {
                float e = __expf(vals[ct][r] - vmax[r]);
                vals[ct][r] = e;
                vsum[r] += e;
            }
#pragma unroll
        for (int d = 1; d < 16; d <<= 1)
#pragma unroll
            for (int r = 0; r < 4; ++r) vsum[r] += __shfl_xor(vsum[r], d);

#pragma unroll
        for (int r = 0; r < 4; ++r) {
            float inv = 1.0f / vsum[r];
            int grow = r0 + rq + r;
#pragma unroll
            for (int ct = 0; ct < 4; ++ct)
                L1out[(size_t)grow * 64 + ct * 16 + ml] = vals[ct][r] * inv;
            if (ml == 0) parent[grow] = vidx[r];
        }
    }
}

// ---------------------------------------------------------------------------
__global__ __launch_bounds__(256, 2) void l2_softmax(
    const float* __restrict__ partials, const void* __restrict__ b22,
    const int* __restrict__ child_parent, const int* __restrict__ parent,
    float* __restrict__ L2out, const int* __restrict__ flagp)
{
    int flag = *flagp;
    int t = threadIdx.x, w = t >> 6, lane = t & 63;
    int row = blockIdx.x * 4 + w;
    int c4 = lane * 4;

    float v[4] = {0.f, 0.f, 0.f, 0.f};
#pragma unroll
    for (int kc = 0; kc < 4; ++kc) {
        float4 pv = *(const float4*)(partials + ((size_t)kc * 8192 + row) * 256 + c4);
        v[0] += pv.x; v[1] += pv.y; v[2] += pv.z; v[3] += pv.w;
    }
    int par = parent[row];
#pragma unroll
    for (int j = 0; j < 4; ++j) {
        float x = v[j] + rd_any(b22, c4 + j, flag);
        x = x > 0.f ? x : 0.f;
        if (child_parent[c4 + j] != par) x += MASK_VALUE;
        v[j] = x;
    }
    float m = fmaxf(fmaxf(v[0], v[1]), fmaxf(v[2], v[3]));
#pragma unroll
    for (int d = 1; d < 64; d <<= 1) m = fmaxf(m, __shfl_xor(m, d));
    float sum = 0.f;
#pragma unroll
    for (int j = 0; j < 4; ++j) { v[j] = __expf(v[j] - m); sum += v[j]; }
#pragma unroll
    for (int d = 1; d < 64; d <<= 1) sum += __shfl_xor(sum, d);
    float inv = 1.0f / sum;
    float4 o = {v[0] * inv, v[1] * inv, v[2] * inv, v[3] * inv};
    *(float4*)(L2out + (size_t)row * 256 + c4) = o;
}

// ---------------------------------------------------------------------------
extern "C" void kernel_launch(void* const* d_in, const int* in_sizes, int n_in,
                              void* d_out, int out_size, void* d_ws, size_t ws_size,
                              hipStream_t stream) {
    (void)in_sizes; (void)n_in; (void)out_size; (void)ws_size;

    const void* x    = d_in[0];
    const void* W1_1 = d_in[1];
    const void* b1_1 = d_in[2];
    const void* W1_2 = d_in[3];
    const void* b1_2 = d_in[4];
    const void* W2_1 = d_in[5];
    const void* b2_1 = d_in[6];
    const void* W2_2 = d_in[7];
    const void* b2_2 = d_in[8];
    const int* child_parent = (const int*)d_in[9];

    // ws layout, 183 MB total:
    char* p = (char*)d_ws;
    _Float16* xh    = (_Float16*)(p);                 // 16 MB [8192][1024]
    _Float16* xl    = (_Float16*)(p + 16777216);      // 16 MB
    _Float16* whT   = (_Float16*)(p + 33554432);      //  4 MB [2048][1024]
    _Float16* wlT   = (_Float16*)(p + 37748736);      //  4 MB
    _Float16* h1h   = (_Float16*)(p + 41943040);      // 32 MB [8192][2048]
    _Float16* h1l   = (_Float16*)(p + 75497472);      // 32 MB
    _Float16* h2b   = (_Float16*)(p + 109051904);     // 32 MB [8192][2048]
    _Float16* W2Tf  = (_Float16*)(p + 142606336);     //  4 MB [2048][1024]
    _Float16* W22Tf = (_Float16*)(p + 146800640);     //  2 MB [256][4096]
    _Float16* w12h  = (_Float16*)(p + 148897792);     // 256 KB [64][2048]
    _Float16* w12l  = (_Float16*)(p + 149159936);     // 256 KB
    float* partials = (float*)(p + 149422080);        // 32 MB [4][8192][256]
    int* parent     = (int*)(p + 182976512);          // 32 KB
    int* flag       = (int*)(p + 183009280);

    float* L1out = (float*)d_out;
    float* L2out = L1out + (size_t)8192 * 64;

    hipLaunchKernelGGL(detect_dtype, dim3(1), dim3(256), 0, stream,
                       (const unsigned int*)x, flag);
    hipLaunchKernelGGL(prep_all, dim3(9504), dim3(256), 0, stream,
                       x, W1_1, W2_1, W2_2, W1_2,
                       xh, xl, whT, wlT, W2Tf, W22Tf, w12h, w12l, flag);
    hipLaunchKernelGGL(h12_gemm8, dim3(768), dim3(512), 0, stream,
                       xh, xl, whT, wlT, b1_1, W2Tf, b2_1,
                       h1h, h1l, h2b, flag);
    hipLaunchKernelGGL(head_fused, dim3(1024), dim3(256), 0, stream,
                       h1h, h1l, h2b, W22Tf, partials,
                       w12h, w12l, b1_2, L1out, parent, flag);
    hipLaunchKernelGGL(l2_softmax, dim3(2048), dim3(256), 0, stream,
                       partials, b2_2, child_parent, parent, L2out, flag);
}

// Round 5
// 331.709 us; speedup vs baseline: 1.0764x; 1.0764x over previous
//
#include <hip/hip_runtime.h>
#include <hip/hip_bf16.h>
#include <stdint.h>
#include <math.h>

// ---------------------------------------------------------------------------
// HMC hierarchical classifier (B=8192, F=1024, H=2048, L1N=64, L2N=256).
// f32-accurate GEMMs via 2-plane f16 split (Ootomo): v = vh + vl*2^-11,
// 3 MFMAs / 2 accumulators, dropped ll ~ 2^-22 rel.
// R15: (a) h12_gemm8 reverted to R13 exactly (R14's hoist spilled: +31MB
// scratch writes, 270us cold dispatch; R13 = proven 134.5us, VGPR budget
// 128V+128A is saturated). (b) head_fused l2_gemm ported to the R13
// slot-ring: ring-3 x 16KiB slots, VMW(4)/slot, counted lgkm(2)/(0),
// MFMA rt01/rt23 split across the barrier, bfa/bfb double-buffer,
// hoisted ds-bases (4-wave kernel has register headroom, no spill risk).
// prep_all / l1_mfma / l2_softmax unchanged.
// ---------------------------------------------------------------------------

typedef _Float16 f16x8 __attribute__((ext_vector_type(8)));
typedef float    f32x4 __attribute__((ext_vector_type(4)));

#define MASK_VALUE (-10000.0f)
#define SWZ(r) ((((r) + ((r) >> 2))) & 3)          // legacy swizzle (prep/old)
#define SW4(row, c) ((c) ^ (((row) >> 1) & 3))     // slot swizzle
#define RSCALE 2048.0f
#define INV_RSCALE (1.0f / 2048.0f)

#define GLOBAL_AS __attribute__((address_space(1)))
#define LDS_AS    __attribute__((address_space(3)))

__device__ __forceinline__ void gload16(const void* g, void* lds) {
    __builtin_amdgcn_global_load_lds((const GLOBAL_AS void*)g, (LDS_AS void*)lds, 16, 0, 0);
}

__device__ __forceinline__ float rd_any(const void* p, size_t i, int flag) {
    return flag ? (float)((const __hip_bfloat16*)p)[i] : ((const float*)p)[i];
}

__device__ __forceinline__ void wg_bar() {
    asm volatile("" ::: "memory");
    __builtin_amdgcn_s_barrier();
    asm volatile("" ::: "memory");
}
#define LGKMN(n) do { asm volatile("s_waitcnt lgkmcnt(" #n ")" ::: "memory"); \
                      __builtin_amdgcn_sched_barrier(0); } while (0)
#define VMW(n)  asm volatile("s_waitcnt vmcnt(" #n ")" ::: "memory")
#define SB0()   __builtin_amdgcn_sched_barrier(0)
#define MFMA16(a,b,c) __builtin_amdgcn_mfma_f32_16x16x32_f16((a),(b),(c),0,0,0)

// ---------------------------------------------------------------------------
__global__ void detect_dtype(const unsigned int* __restrict__ x, int* __restrict__ flag) {
    __shared__ int cnt;
    if (threadIdx.x == 0) cnt = 0;
    __syncthreads();
    int local = 0;
#pragma unroll
    for (int i = 0; i < 4; ++i) {
        unsigned int w = x[threadIdx.x * 4 + i];
        unsigned int e = (w >> 7) & 0xFFu;
        if (e >= 96u && e <= 144u) local++;
    }
    atomicAdd(&cnt, local);
    __syncthreads();
    if (threadIdx.x == 0) *flag = (cnt >= 600) ? 1 : 0;   // 1 = bf16 inputs
}

// ---------------------------------------------------------------------------
// prep_all: fused prep.  Sections (by blockIdx.x):
//   [0,8192)      split_x        (x -> xh, xl)
//   [8192,8704)   split_w1t      (W1_1 -> whT, wlT)   32x16 tiles
//   [8704,9216)   transpose W2_1 -> W2Tf  [2048][1024] 32x16 tiles
//   [9216,9472)   transpose W2_2 -> W22Tf [256][4096]   4x64 tiles
//   [9472,9504)   split_w12t     (W1_2 -> w12h, w12l)  32 tiles
// ---------------------------------------------------------------------------
__global__ void prep_all(
    const void* __restrict__ x, const void* __restrict__ W1_1,
    const void* __restrict__ W2_1, const void* __restrict__ W2_2,
    const void* __restrict__ W1_2,
    _Float16* __restrict__ xh, _Float16* __restrict__ xl,
    _Float16* __restrict__ whT, _Float16* __restrict__ wlT,
    _Float16* __restrict__ W2Tf, _Float16* __restrict__ W22Tf,
    _Float16* __restrict__ w12h, _Float16* __restrict__ w12l,
    const int* __restrict__ flagp)
{
    __shared__ __align__(16) float tile[64][65];
    int flag = *flagp;
    int bid = blockIdx.x, t = threadIdx.x;
    int tx = t & 63, ty = t >> 6;

    if (bid < 8192) {
        size_t i = ((size_t)bid * 256 + t) * 4;
#pragma unroll
        for (int j = 0; j < 4; ++j) {
            float a = rd_any(x, i + j, flag);
            _Float16 h = (_Float16)a;
            xh[i + j] = h;
            xl[i + j] = (_Float16)((a - (float)h) * RSCALE);
        }
        return;
    }

    if (bid < 8704) {                       // split_w1t: [1024][2048] -> T
        int b = bid - 8192;
        int c0 = (b & 31) * 64, r0 = (b >> 5) * 64;
#pragma unroll
        for (int i = 0; i < 16; ++i) {
            int r = ty + i * 4;
            tile[r][tx] = rd_any(W1_1, (size_t)(r0 + r) * 2048 + c0 + tx, flag);
        }
        __syncthreads();
#pragma unroll
        for (int i = 0; i < 16; ++i) {
            int r = ty + i * 4;
            size_t o = (size_t)(c0 + r) * 1024 + r0 + tx;
            float a = tile[tx][r];
            _Float16 h = (_Float16)a;
            whT[o] = h;
            wlT[o] = (_Float16)((a - (float)h) * RSCALE);
        }
        return;
    }

    if (bid < 9216) {                       // W2_1 [1024][2048] -> W2Tf
        int b = bid - 8704;
        int c0 = (b & 31) * 64, r0 = (b >> 5) * 64;
#pragma unroll
        for (int i = 0; i < 16; ++i) {
            int r = ty + i * 4;
            tile[r][tx] = rd_any(W2_1, (size_t)(r0 + r) * 2048 + c0 + tx, flag);
        }
        __syncthreads();
#pragma unroll
        for (int i = 0; i < 16; ++i) {
            int r = ty + i * 4;
            W2Tf[(size_t)(c0 + r) * 1024 + r0 + tx] = (_Float16)tile[tx][r];
        }
        return;
    }

    if (bid < 9472) {                       // W2_2 [4096][256] -> W22Tf
        int b = bid - 9216;
        int c0 = (b & 3) * 64, r0 = (b >> 2) * 64;
#pragma unroll
        for (int i = 0; i < 16; ++i) {
            int r = ty + i * 4;
            tile[r][tx] = rd_any(W2_2, (size_t)(r0 + r) * 256 + c0 + tx, flag);
        }
        __syncthreads();
#pragma unroll
        for (int i = 0; i < 16; ++i) {
            int r = ty + i * 4;
            W22Tf[(size_t)(c0 + r) * 4096 + r0 + tx] = (_Float16)tile[tx][r];
        }
        return;
    }

    {                                       // split_w12t: [2048][64] -> T
        int b = bid - 9472;
        int r0 = b * 64;
#pragma unroll
        for (int i = 0; i < 16; ++i) {
            int r = ty + i * 4;
            tile[r][tx] = rd_any(W1_2, (size_t)(r0 + r) * 64 + tx, flag);
        }
        __syncthreads();
#pragma unroll
        for (int i = 0; i < 16; ++i) {
            int r = ty + i * 4;
            size_t o = (size_t)r * 2048 + r0 + tx;
            float a = tile[tx][r];
            _Float16 h = (_Float16)a;
            w12h[o] = h;
            w12l[o] = (_Float16)((a - (float)h) * RSCALE);
        }
    }
}

// ---------------------------------------------------------------------------
// h12_gemm8: R13 skewed counted-lgkm slot-ring schedule, ONE barrier per
// slot (byte-identical to the proven R13 kernel).
// ---------------------------------------------------------------------------
__global__ __launch_bounds__(512, 2) void h12_gemm8(
    const _Float16* __restrict__ xh, const _Float16* __restrict__ xl,
    const _Float16* __restrict__ whT, const _Float16* __restrict__ wlT,
    const void* __restrict__ b11,
    const _Float16* __restrict__ W2Tf, const void* __restrict__ b21,
    _Float16* __restrict__ h1h, _Float16* __restrict__ h1l,
    _Float16* __restrict__ h2b,
    const int* __restrict__ flagp)
{
    __shared__ __align__(16) char smem[147456];
    int flag = *flagp;
    int t = threadIdx.x, w = t >> 6, lane = t & 63;
    int ml = lane & 15, q = lane >> 4, rq = q * 4;

    int xcd = blockIdx.x & 7, rblk = blockIdx.x >> 3;   // 8 XCDs x 96

    if (rblk < 64) {
        // ================= h1: 3-term, BM=256 BN=128, ring-3 =================
        int lb = xcd * 64 + rblk;
        int mt = lb >> 4, nt = lb & 15;
        int i0 = mt * 256, j0 = nt * 128;
        int wr = w & 3, wc = w >> 2;                    // 4 x 2 waves

        f32x4 acc1[4][4], acc2[4][4];
#pragma unroll
        for (int a = 0; a < 4; ++a)
#pragma unroll
            for (int b = 0; b < 4; ++b) {
                acc1[a][b] = (f32x4){0.f, 0.f, 0.f, 0.f};
                acc2[a][b] = (f32x4){0.f, 0.f, 0.f, 0.f};
            }

        // persistent frag regs: A-planes + two B groups (ct0,1 / ct2,3)
        f16x8 ah[4], al[4], bAh[2], bAl[2], bBh[2], bBl[2];

        // slot layout: Ah @0 (16K), Al @16384 (16K), Bh @32768 (8K), Bl @40960 (8K)
        auto stage = [&](char* bp, int kt, int g) {
            if (g < 4) {                                // g0,1: Ah  g2,3: Al
                int ci = ((g & 1) << 9) + t;            // 0..1023
                int row = ci >> 2;
                int c = SW4(row, ci & 3);
                const _Float16* src = (g < 2) ? xh : xl;
                gload16(src + (size_t)(i0 + row) * 1024 + kt + c * 8,
                        bp + ((g < 2) ? 0 : 16384) + ci * 16);
            } else {                                    // g4: Bh  g5: Bl
                int ci = t;                             // 0..511
                int row = ci >> 2;
                int c = SW4(row, ci & 3);
                const _Float16* src = (g == 4) ? whT : wlT;
                gload16(src + (size_t)(j0 + row) * 1024 + kt + c * 8,
                        bp + ((g == 4) ? 32768 : 40960) + ci * 16);
            }
        };
        auto rdBA = [&](char* bp) {                     // 4 reads: B ct0,1
#pragma unroll
            for (int ct = 0; ct < 2; ++ct) {
                int row = wc * 64 + ct * 16 + ml;
                int off = row * 64 + (SW4(row, q) << 4);
                bAh[ct] = *(const f16x8*)(bp + 32768 + off);
                bAl[ct] = *(const f16x8*)(bp + 40960 + off);
            }
        };
        auto rdA = [&](char* bp) {                      // 8 reads: A planes
#pragma unroll
            for (int rt = 0; rt < 4; ++rt) {
                int row = wr * 64 + rt * 16 + ml;
                int off = row * 64 + (SW4(row, q) << 4);
                ah[rt] = *(const f16x8*)(bp + off);
                al[rt] = *(const f16x8*)(bp + 16384 + off);
            }
        };
        auto rdBB = [&](char* bp) {                     // 4 reads: B ct2,3
#pragma unroll
            for (int ct = 0; ct < 2; ++ct) {
                int row = wc * 64 + (ct + 2) * 16 + ml;
                int off = row * 64 + (SW4(row, q) << 4);
                bBh[ct] = *(const f16x8*)(bp + 32768 + off);
                bBl[ct] = *(const f16x8*)(bp + 40960 + off);
            }
        };

        // prologue: stage slots 0,1; then issue slot-0 reads in invariant order
#pragma unroll
        for (int g = 0; g < 6; ++g) stage(smem, 0, g);
#pragma unroll
        for (int g = 0; g < 6; ++g) stage(smem + 49152, 32, g);
        VMW(6);                                         // slot0 landed
        wg_bar();
        rdBA(smem); SB0();
        rdA(smem);  SB0();
        rdBB(smem); SB0();

        int cur = 0;
        for (int s = 0; s < 32; ++s) {
            char* bpn = smem + ((cur + 1 == 3) ? 0 : cur + 1) * 49152;
            int cur2 = cur + 2; if (cur2 >= 3) cur2 -= 3;
            char* bp2 = smem + cur2 * 49152;
            int kt2 = (s + 2) * 32;
            bool st = (s < 30), rd = (s < 31);

            if (st) {
#pragma unroll
                for (int g = 0; g < 6; ++g) stage(bp2, kt2, g);
            }
            LGKMN(4);                                   // bA, ah/al ready
            __builtin_amdgcn_s_setprio(1);
#pragma unroll
            for (int rt = 0; rt < 4; ++rt)
#pragma unroll
                for (int ct = 0; ct < 2; ++ct) {
                    acc1[rt][ct] = MFMA16(ah[rt], bAh[ct], acc1[rt][ct]);
                    acc2[rt][ct] = MFMA16(ah[rt], bAl[ct], acc2[rt][ct]);
                    acc2[rt][ct] = MFMA16(al[rt], bAh[ct], acc2[rt][ct]);
                }
            __builtin_amdgcn_s_setprio(0);
            LGKMN(0);                                   // bB ready
            if (st) { VMW(6); } else { VMW(0); }        // next slot's LDS landed
            wg_bar();
            if (rd) rdBA(bpn);
            SB0();
            __builtin_amdgcn_s_setprio(1);
#pragma unroll
            for (int rt = 0; rt < 4; ++rt)
#pragma unroll
                for (int ct = 0; ct < 2; ++ct) {
                    acc1[rt][ct + 2] = MFMA16(ah[rt], bBh[ct], acc1[rt][ct + 2]);
                    acc2[rt][ct + 2] = MFMA16(ah[rt], bBl[ct], acc2[rt][ct + 2]);
                    acc2[rt][ct + 2] = MFMA16(al[rt], bBh[ct], acc2[rt][ct + 2]);
                }
            __builtin_amdgcn_s_setprio(0);
            if (rd) { rdA(bpn); SB0(); rdBB(bpn); }     // A planes then bB
            cur = cur + 1; if (cur == 3) cur = 0;
        }

        // ---- epilogue: bias + relu, 2-plane split out via LDS restage ----
#pragma unroll
        for (int ct = 0; ct < 4; ++ct) {
            float bv = rd_any(b11, j0 + wc * 64 + ct * 16 + ml, flag);
#pragma unroll
            for (int rt = 0; rt < 4; ++rt)
#pragma unroll
                for (int rr = 0; rr < 4; ++rr) {
                    float v = acc1[rt][ct][rr] + acc2[rt][ct][rr] * INV_RSCALE + bv;
                    acc1[rt][ct][rr] = v > 0.f ? v : 0.f;
                }
        }
        _Float16* C = (_Float16*)smem;
#pragma unroll
        for (int p = 0; p < 2; ++p) {
            __syncthreads();
#pragma unroll
            for (int rt = 0; rt < 4; ++rt)
#pragma unroll
                for (int ct = 0; ct < 4; ++ct)
#pragma unroll
                    for (int rr = 0; rr < 4; ++rr) {
                        float v = acc1[rt][ct][rr];
                        _Float16 h = (_Float16)v;
                        _Float16 outv = (p == 0) ? h
                                      : (_Float16)((v - (float)h) * RSCALE);
                        int rl = wr * 64 + rt * 16 + rq + rr;
                        int cl = wc * 64 + ct * 16 + ml;
                        C[rl * 136 + cl] = outv;
                    }
            __syncthreads();
            _Float16* dst = (p == 0) ? h1h : h1l;
#pragma unroll
            for (int i = 0; i < 8; ++i) {
                int c = i * 512 + t;
                int row = c >> 4, c8 = (c & 15) * 8;
                *(f16x8*)(dst + (size_t)(i0 + row) * 2048 + j0 + c8) =
                    *(const f16x8*)(C + row * 136 + c8);
            }
        }
    } else {
        // ================= h2: 1-term, BM=256 BN=256, ring-4 =================
        int lb = xcd * 32 + (rblk - 64);
        int mt = lb >> 3, nt = lb & 7;
        int i0 = mt * 256, j0 = nt * 256;
        int wr = w & 1, wc = w >> 1;                    // 2 x 4 waves

        f32x4 acc[8][4];
#pragma unroll
        for (int a = 0; a < 8; ++a)
#pragma unroll
            for (int b = 0; b < 4; ++b) acc[a][b] = (f32x4){0.f, 0.f, 0.f, 0.f};

        // persistent frags: af rt0-3, af rt4-7, bf double-buffer (static names)
        f16x8 af0[4], af4[4], bfa[4], bfb[4];

        // slot layout: A @0 (16K), B @16384 (16K)
        auto stage = [&](char* bp, int kt, int g) {
            int ci = ((g & 1) << 9) + t;                // 0..1023
            int row = ci >> 2;
            int c = SW4(row, ci & 3);
            if (g < 2)
                gload16(xh + (size_t)(i0 + row) * 1024 + kt + c * 8,
                        bp + ci * 16);
            else
                gload16(W2Tf + (size_t)(j0 + row) * 1024 + kt + c * 8,
                        bp + 16384 + ci * 16);
        };
        auto rdBF = [&](char* bp, f16x8* dst) {         // 4 reads: all B ct
#pragma unroll
            for (int ct = 0; ct < 4; ++ct) {
                int row = wc * 64 + ct * 16 + ml;
                int off = row * 64 + (SW4(row, q) << 4);
                dst[ct] = *(const f16x8*)(bp + 16384 + off);
            }
        };
        auto rdA0 = [&](char* bp) {                     // 4 reads: rt0-3
#pragma unroll
            for (int rt = 0; rt < 4; ++rt) {
                int row = wr * 128 + rt * 16 + ml;
                int off = row * 64 + (SW4(row, q) << 4);
                af0[rt] = *(const f16x8*)(bp + off);
            }
        };
        auto rdA4 = [&](char* bp) {                     // 4 reads: rt4-7
#pragma unroll
            for (int rt = 0; rt < 4; ++rt) {
                int row = wr * 128 + (rt + 4) * 16 + ml;
                int off = row * 64 + (SW4(row, q) << 4);
                af4[rt] = *(const f16x8*)(bp + off);
            }
        };

#pragma unroll
        for (int g = 0; g < 4; ++g) stage(smem, 0, g);
#pragma unroll
        for (int g = 0; g < 4; ++g) stage(smem + 32768, 32, g);
        VMW(4);
        wg_bar();
        rdBF(smem, bfa); SB0();
        rdA0(smem);      SB0();
        rdA4(smem);      SB0();

        int cur = 0;
        // one slot body; BFC = current bf regs, BFN = next bf regs
        auto body = [&](int s, f16x8* BFC, f16x8* BFN) {
            char* bpn = smem + ((cur + 1) & 3) * 32768;
            char* bp2 = smem + ((cur + 2) & 3) * 32768;
            int kt2 = (s + 2) * 32;
            bool st = (s < 30), rd = (s < 31);

            if (st) {
#pragma unroll
                for (int g = 0; g < 4; ++g) stage(bp2, kt2, g);
            }
            LGKMN(4);                                   // BFC, af0 ready
            __builtin_amdgcn_s_setprio(1);
#pragma unroll
            for (int rt = 0; rt < 4; ++rt)
#pragma unroll
                for (int ct = 0; ct < 4; ++ct)
                    acc[rt][ct] = MFMA16(af0[rt], BFC[ct], acc[rt][ct]);
            __builtin_amdgcn_s_setprio(0);
            LGKMN(0);                                   // af4 ready
            if (st) { VMW(4); } else { VMW(0); }
            wg_bar();
            if (rd) { rdBF(bpn, BFN); rdA0(bpn); }      // first-8 of s+1
            SB0();
            __builtin_amdgcn_s_setprio(1);
#pragma unroll
            for (int rt = 0; rt < 4; ++rt)
#pragma unroll
                for (int ct = 0; ct < 4; ++ct)
                    acc[rt + 4][ct] = MFMA16(af4[rt], BFC[ct], acc[rt + 4][ct]);
            __builtin_amdgcn_s_setprio(0);
            if (rd) rdA4(bpn);                          // last-4 of s+1
            cur = (cur + 1) & 3;
        };

        for (int k = 0; k < 16; ++k) {
            body(2 * k,     bfa, bfb);
            body(2 * k + 1, bfb, bfa);
        }

        // ---- epilogue: bias + relu, f16 out via LDS restage ----
        _Float16* C = (_Float16*)smem;
        __syncthreads();
#pragma unroll
        for (int ct = 0; ct < 4; ++ct) {
            float bv = rd_any(b21, j0 + wc * 64 + ct * 16 + ml, flag);
#pragma unroll
            for (int rt = 0; rt < 8; ++rt)
#pragma unroll
                for (int rr = 0; rr < 4; ++rr) {
                    float v = acc[rt][ct][rr] + bv;
                    v = v > 0.f ? v : 0.f;
                    int rl = wr * 128 + rt * 16 + rq + rr;
                    int cl = wc * 64 + ct * 16 + ml;
                    C[rl * 264 + cl] = (_Float16)v;
                }
        }
        __syncthreads();
#pragma unroll
        for (int i = 0; i < 16; ++i) {
            int c = i * 512 + t;
            int row = c >> 5, c8 = (c & 31) * 8;
            *(f16x8*)(h2b + (size_t)(i0 + row) * 2048 + j0 + c8) =
                *(const f16x8*)(C + row * 264 + c8);
        }
    }
}

// ---------------------------------------------------------------------------
// head_fused: blocks [0,512) = l2_gemm (slot-ring, R15); [512,1024) =
// l1_mfma (L1 softmax + argmax).  Both read only h-planes; independent.
// ---------------------------------------------------------------------------
__global__ __launch_bounds__(256, 2) void head_fused(
    const _Float16* __restrict__ h1h, const _Float16* __restrict__ h1l,
    const _Float16* __restrict__ h2b, const _Float16* __restrict__ W22T,
    float* __restrict__ partials,
    const _Float16* __restrict__ w12h, const _Float16* __restrict__ w12l,
    const void* __restrict__ b12, float* __restrict__ L1out,
    int* __restrict__ parent, const int* __restrict__ flagp)
{
    __shared__ __align__(16) char smem[49152];
    int flag = *flagp;
    int t = threadIdx.x, w = t >> 6, lane = t & 63;
    int ml = lane & 15, q = lane >> 4;

    if (blockIdx.x < 512) {
        // ----- l2_gemm: ring-3 x 16KiB slots, skewed counted-lgkm -----
        int bid = blockIdx.x;
        int g = bid & 7, s = bid >> 3;
        int mt = g * 8 + (s & 7);
        int rest = s >> 3;
        int nt = rest & 1, kc = rest >> 1;
        int i0 = mt * 128, j0 = nt * 128;
        const _Float16* Abase = (kc < 2) ? h1h : h2b;
        int kof = (kc & 1) * 1024;
        int wr = w & 1, wc2 = w >> 1;

        f32x4 acc[4][4];
#pragma unroll
        for (int a = 0; a < 4; ++a)
#pragma unroll
            for (int b = 0; b < 4; ++b) acc[a][b] = (f32x4){0.f, 0.f, 0.f, 0.f};

        // persistent frags: A rt0,1 / rt2,3; B double-buffer
        f16x8 af0[2], af4[2], bfa[4], bfb[4];

        int t16 = t * 16;
        int swz16 = (q ^ ((ml >> 1) & 3)) << 4;
        int r0g = t >> 2;
        int c0g = (t & 3) ^ ((t >> 3) & 3);

        // ds bases per ring slot (A @0 8K, B @8192 8K within 16KiB slot)
        int aA0 = (wr * 64 + ml) * 64 + swz16;
        int aA1 = aA0 + 16384, aA2 = aA0 + 32768;
        int aB0 = 8192 + (wc2 * 64 + ml) * 64 + swz16;
        int aB1 = aB0 + 16384, aB2 = aB0 + 32768;

        // persistent global staging pointers (byte), += 64 per slot
        const char* pA = (const char*)Abase + (size_t)(i0 + r0g) * 4096
                         + (size_t)(kof + c0g * 8) * 2;
        const char* pB = (const char*)W22T + (size_t)(j0 + r0g) * 8192
                         + (size_t)(kc * 1024 + c0g * 8) * 2;

        auto stage = [&](int slotB) {                   // 4 gloads
            gload16(pA,          smem + slotB + t16);
            gload16(pA + 262144, smem + slotB + 4096 + t16);
            gload16(pB,          smem + slotB + 8192 + t16);
            gload16(pB + 524288, smem + slotB + 12288 + t16);
            pA += 64; pB += 64;
        };
        auto rdBF = [&](int aB, f16x8* dst) {           // 4 reads: all B ct
            dst[0] = *(const f16x8*)(smem + aB);
            dst[1] = *(const f16x8*)(smem + aB + 1024);
            dst[2] = *(const f16x8*)(smem + aB + 2048);
            dst[3] = *(const f16x8*)(smem + aB + 3072);
        };
        auto rdA0 = [&](int aA) {                       // 2 reads: rt0,1
            af0[0] = *(const f16x8*)(smem + aA);
            af0[1] = *(const f16x8*)(smem + aA + 1024);
        };
        auto rdA4 = [&](int aA) {                       // 2 reads: rt2,3
            af4[0] = *(const f16x8*)(smem + aA + 2048);
            af4[1] = *(const f16x8*)(smem + aA + 3072);
        };

        auto slot = [&](int aAn, int aBn, int pfB, bool st, bool rd,
                        f16x8* BFC, f16x8* BFN) {
            if (st) stage(pfB);
            LGKMN(2);                                   // BFC(4)+af0(2) ready
            __builtin_amdgcn_s_setprio(1);
#pragma unroll
            for (int rt = 0; rt < 2; ++rt)
#pragma unroll
                for (int ct = 0; ct < 4; ++ct)
                    acc[rt][ct] = MFMA16(af0[rt], BFC[ct], acc[rt][ct]);
            __builtin_amdgcn_s_setprio(0);
            LGKMN(0);                                   // af4 ready
            if (st) { VMW(4); } else { VMW(0); }        // slot s+1 landed
            wg_bar();
            if (rd) { rdBF(aBn, BFN); rdA0(aAn); }
            SB0();
            __builtin_amdgcn_s_setprio(1);
#pragma unroll
            for (int rt = 0; rt < 2; ++rt)
#pragma unroll
                for (int ct = 0; ct < 4; ++ct)
                    acc[rt + 2][ct] = MFMA16(af4[rt], BFC[ct], acc[rt + 2][ct]);
            __builtin_amdgcn_s_setprio(0);
            if (rd) rdA4(aAn);
            SB0();
        };

        // prologue: stage slots 0,1; issue slot-0 reads [bf][af0][af4]
        stage(0);
        stage(16384);
        VMW(4);                                         // slot0 landed
        wg_bar();
        rdBF(aB0, bfa); SB0();
        rdA0(aA0);      SB0();
        rdA4(aA0);      SB0();

        for (int it = 0; it < 5; ++it) {                // slots 0..29
            slot(aA1, aB1, 32768, true, true, bfa, bfb);   // s%6=0 cur0 pf2
            slot(aA2, aB2, 0,     true, true, bfb, bfa);   // s%6=1 cur1 pf0
            slot(aA0, aB0, 16384, true, true, bfa, bfb);   // s%6=2 cur2 pf1
            slot(aA1, aB1, 32768, true, true, bfb, bfa);   // s%6=3 cur0 pf2
            slot(aA2, aB2, 0,     true, true, bfa, bfb);   // s%6=4 cur1 pf0
            slot(aA0, aB0, 16384, true, true, bfb, bfa);   // s%6=5 cur2 pf1
        }
        slot(aA1, aB1, 0, false, true,  bfa, bfb);      // s=30 (cur0)
        slot(aA2, aB2, 0, false, false, bfb, bfa);      // s=31 (cur1)

        // ---- epilogue: write f32 partials ----
        float* out = partials + (size_t)kc * 8192 * 256;
        int rq = (lane >> 4) * 4;
#pragma unroll
        for (int ct = 0; ct < 4; ++ct) {
            int nl = j0 + wc2 * 64 + ct * 16 + ml;
#pragma unroll
            for (int rt = 0; rt < 4; ++rt) {
                int mbase = i0 + wr * 64 + rt * 16 + rq;
#pragma unroll
                for (int r = 0; r < 4; ++r)
                    out[(size_t)(mbase + r) * 256 + nl] = acc[rt][ct][r];
            }
        }
    } else {
        // ----- l1_mfma: 16 rows/block, 4-wave K-split, 3-term -----
        float* red = (float*)smem;          // [3][4][256] floats = 12 KB
        int r0 = (blockIdx.x - 512) * 16;
        int kq = (lane >> 4) * 8;

        f32x4 acch[4], accx[4];
#pragma unroll
        for (int ct = 0; ct < 4; ++ct) {
            acch[ct] = (f32x4){0.f, 0.f, 0.f, 0.f};
            accx[ct] = (f32x4){0.f, 0.f, 0.f, 0.f};
        }

        size_t aoff = (size_t)(r0 + ml) * 2048 + w * 512 + kq;
        const _Float16* Ah = h1h + aoff;
        const _Float16* Al = h1l + aoff;
        size_t boff[4];
#pragma unroll
        for (int ct = 0; ct < 4; ++ct)
            boff[ct] = (size_t)(ct * 16 + ml) * 2048 + w * 512 + kq;

        f16x8 ah = *(const f16x8*)(Ah), al = *(const f16x8*)(Al);
        f16x8 bh[4], bl[4];
#pragma unroll
        for (int ct = 0; ct < 4; ++ct) {
            bh[ct] = *(const f16x8*)(w12h + boff[ct]);
            bl[ct] = *(const f16x8*)(w12l + boff[ct]);
        }

        for (int kt = 0; kt < 512; kt += 32) {
            int nk = (kt + 32) & 511;
            f16x8 nah = *(const f16x8*)(Ah + nk);
            f16x8 nal = *(const f16x8*)(Al + nk);
            f16x8 nbh[4], nbl[4];
#pragma unroll
            for (int ct = 0; ct < 4; ++ct) {
                nbh[ct] = *(const f16x8*)(w12h + boff[ct] + nk);
                nbl[ct] = *(const f16x8*)(w12l + boff[ct] + nk);
            }
#pragma unroll
            for (int ct = 0; ct < 4; ++ct) {
                acch[ct] = __builtin_amdgcn_mfma_f32_16x16x32_f16(ah, bh[ct], acch[ct], 0, 0, 0);
                accx[ct] = __builtin_amdgcn_mfma_f32_16x16x32_f16(ah, bl[ct], accx[ct], 0, 0, 0);
                accx[ct] = __builtin_amdgcn_mfma_f32_16x16x32_f16(al, bh[ct], accx[ct], 0, 0, 0);
            }
            ah = nah; al = nal;
#pragma unroll
            for (int ct = 0; ct < 4; ++ct) { bh[ct] = nbh[ct]; bl[ct] = nbl[ct]; }
        }

        f32x4 acc[4];
#pragma unroll
        for (int ct = 0; ct < 4; ++ct)
#pragma unroll
            for (int i = 0; i < 4; ++i)
                acc[ct][i] = acch[ct][i] + accx[ct][i] * INV_RSCALE;

        if (w > 0) {
#pragma unroll
            for (int ct = 0; ct < 4; ++ct)
#pragma unroll
                for (int i = 0; i < 4; ++i)
                    red[((w - 1) * 4 + ct) * 256 + lane * 4 + i] = acc[ct][i];
        }
        __syncthreads();
        if (w != 0) return;

#pragma unroll
        for (int wv = 0; wv < 3; ++wv)
#pragma unroll
            for (int ct = 0; ct < 4; ++ct)
#pragma unroll
                for (int i = 0; i < 4; ++i)
                    acc[ct][i] += red[(wv * 4 + ct) * 256 + lane * 4 + i];

        int rq = (lane >> 4) * 4;
        float vals[4][4];
        float vmax[4] = {-1e30f, -1e30f, -1e30f, -1e30f};
        int vidx[4] = {1 << 30, 1 << 30, 1 << 30, 1 << 30};
#pragma unroll
        for (int ct = 0; ct < 4; ++ct) {
            int col = ct * 16 + ml;
            float bv = rd_any(b12, col, flag);
#pragma unroll
            for (int r = 0; r < 4; ++r) {
                float v = acc[ct][r] + bv;
                v = v > 0.f ? v : 0.f;
                vals[ct][r] = v;
                if (v > vmax[r] || (v == vmax[r] && col < vidx[r])) { vmax[r] = v; vidx[r] = col; }
            }
        }
#pragma unroll
        for (int d = 1; d < 16; d <<= 1) {
#pragma unroll
            for (int r = 0; r < 4; ++r) {
                float om = __shfl_xor(vmax[r], d);
                int oi = __shfl_xor(vidx[r], d);
                if (om > vmax[r] || (om == vmax[r] && oi < vidx[r])) { vmax[r] = om; vidx[r] = oi; }
            }
        }
        float vsum[4] = {0.f, 0.f, 0.f, 0.f};
#pragma unroll
        for (int ct = 0; ct < 4; ++ct)
#pragma unroll
            for (int r = 0; r < 4; ++r) {
                float e = __expf(vals[ct][r] - vmax[r]);
                vals[ct][r] = e;
                vsum[r] += e;
            }
#pragma unroll
        for (int d = 1; d < 16; d <<= 1)
#pragma unroll
            for (int r = 0; r < 4; ++r) vsum[r] += __shfl_xor(vsum[r], d);

#pragma unroll
        for (int r = 0; r < 4; ++r) {
            float inv = 1.0f / vsum[r];
            int grow = r0 + rq + r;
#pragma unroll
            for (int ct = 0; ct < 4; ++ct)
                L1out[(size_t)grow * 64 + ct * 16 + ml] = vals[ct][r] * inv;
            if (ml == 0) parent[grow] = vidx[r];
        }
    }
}

// ---------------------------------------------------------------------------
__global__ __launch_bounds__(256, 2) void l2_softmax(
    const float* __restrict__ partials, const void* __restrict__ b22,
    const int* __restrict__ child_parent, const int* __restrict__ parent,
    float* __restrict__ L2out, const int* __restrict__ flagp)
{
    int flag = *flagp;
    int t = threadIdx.x, w = t >> 6, lane = t & 63;
    int row = blockIdx.x * 4 + w;
    int c4 = lane * 4;

    float v[4] = {0.f, 0.f, 0.f, 0.f};
#pragma unroll
    for (int kc = 0; kc < 4; ++kc) {
        float4 pv = *(const float4*)(partials + ((size_t)kc * 8192 + row) * 256 + c4);
        v[0] += pv.x; v[1] += pv.y; v[2] += pv.z; v[3] += pv.w;
    }
    int par = parent[row];
#pragma unroll
    for (int j = 0; j < 4; ++j) {
        float x = v[j] + rd_any(b22, c4 + j, flag);
        x = x > 0.f ? x : 0.f;
        if (child_parent[c4 + j] != par) x += MASK_VALUE;
        v[j] = x;
    }
    float m = fmaxf(fmaxf(v[0], v[1]), fmaxf(v[2], v[3]));
#pragma unroll
    for (int d = 1; d < 64; d <<= 1) m = fmaxf(m, __shfl_xor(m, d));
    float sum = 0.f;
#pragma unroll
    for (int j = 0; j < 4; ++j) { v[j] = __expf(v[j] - m); sum += v[j]; }
#pragma unroll
    for (int d = 1; d < 64; d <<= 1) sum += __shfl_xor(sum, d);
    float inv = 1.0f / sum;
    float4 o = {v[0] * inv, v[1] * inv, v[2] * inv, v[3] * inv};
    *(float4*)(L2out + (size_t)row * 256 + c4) = o;
}

// ---------------------------------------------------------------------------
extern "C" void kernel_launch(void* const* d_in, const int* in_sizes, int n_in,
                              void* d_out, int out_size, void* d_ws, size_t ws_size,
                              hipStream_t stream) {
    (void)in_sizes; (void)n_in; (void)out_size; (void)ws_size;

    const void* x    = d_in[0];
    const void* W1_1 = d_in[1];
    const void* b1_1 = d_in[2];
    const void* W1_2 = d_in[3];
    const void* b1_2 = d_in[4];
    const void* W2_1 = d_in[5];
    const void* b2_1 = d_in[6];
    const void* W2_2 = d_in[7];
    const void* b2_2 = d_in[8];
    const int* child_parent = (const int*)d_in[9];

    // ws layout, 183 MB total:
    char* p = (char*)d_ws;
    _Float16* xh    = (_Float16*)(p);                 // 16 MB [8192][1024]
    _Float16* xl    = (_Float16*)(p + 16777216);      // 16 MB
    _Float16* whT   = (_Float16*)(p + 33554432);      //  4 MB [2048][1024]
    _Float16* wlT   = (_Float16*)(p + 37748736);      //  4 MB
    _Float16* h1h   = (_Float16*)(p + 41943040);      // 32 MB [8192][2048]
    _Float16* h1l   = (_Float16*)(p + 75497472);      // 32 MB
    _Float16* h2b   = (_Float16*)(p + 109051904);     // 32 MB [8192][2048]
    _Float16* W2Tf  = (_Float16*)(p + 142606336);     //  4 MB [2048][1024]
    _Float16* W22Tf = (_Float16*)(p + 146800640);     //  2 MB [256][4096]
    _Float16* w12h  = (_Float16*)(p + 148897792);     // 256 KB [64][2048]
    _Float16* w12l  = (_Float16*)(p + 149159936);     // 256 KB
    float* partials = (float*)(p + 149422080);        // 32 MB [4][8192][256]
    int* parent     = (int*)(p + 182976512);          // 32 KB
    int* flag       = (int*)(p + 183009280);

    float* L1out = (float*)d_out;
    float* L2out = L1out + (size_t)8192 * 64;

    hipLaunchKernelGGL(detect_dtype, dim3(1), dim3(256), 0, stream,
                       (const unsigned int*)x, flag);
    hipLaunchKernelGGL(prep_all, dim3(9504), dim3(256), 0, stream,
                       x, W1_1, W2_1, W2_2, W1_2,
                       xh, xl, whT, wlT, W2Tf, W22Tf, w12h, w12l, flag);
    hipLaunchKernelGGL(h12_gemm8, dim3(768), dim3(512), 0, stream,
                       xh, xl, whT, wlT, b1_1, W2Tf, b2_1,
                       h1h, h1l, h2b, flag);
    hipLaunchKernelGGL(head_fused, dim3(1024), dim3(256), 0, stream,
                       h1h, h1l, h2b, W22Tf, partials,
                       w12h, w12l, b1_2, L1out, parent, flag);
    hipLaunchKernelGGL(l2_softmax, dim3(2048), dim3(256), 0, stream,
                       partials, b2_2, child_parent, parent, L2out, flag);
}

// Round 6
// 319.129 us; speedup vs baseline: 1.1189x; 1.0394x over previous
//
#include <hip/hip_runtime.h>
#include <hip/hip_bf16.h>
#include <stdint.h>
#include <math.h>

// ---------------------------------------------------------------------------
// HMC hierarchical classifier (B=8192, F=1024, H=2048, L1N=64, L2N=256).
// f32-accurate GEMMs via 2-plane f16 split (Ootomo): v = vh + vl*2^-11,
// 3 MFMAs / 2 accumulators, dropped ll ~ 2^-22 rel.
// R16: (a) h12 h1-branch MFMA split by A-rt instead of B-ct: post-barrier
// cluster2b uses only {ah23,al23,bh23,bl23}, so rdBA+rdAlow of slot s+1
// (8 reads) issue BEFORE it; only rdBB (4 reads) stays exposed (was 12).
// rdAhigh moves to slot top, drains under cluster1 via LGKMN(4)/LGKMN(0).
// Zero new registers (bh[4]/bl[4] = old bA+bB).  (b) head_fused reverted
// to R13 16KB version (R15's 48KB ring capped l1_mfma at 3 blocks/CU,
// rest +10us).  (c) prep_all split_x vectorized (float4/ushort4 in,
// f16x4 out).  h2 branch / l2_softmax unchanged.
// ---------------------------------------------------------------------------

typedef _Float16 f16x8 __attribute__((ext_vector_type(8)));
typedef _Float16 f16x4 __attribute__((ext_vector_type(4)));
typedef float    f32x4 __attribute__((ext_vector_type(4)));
typedef unsigned short u16x4 __attribute__((ext_vector_type(4)));

#define MASK_VALUE (-10000.0f)
#define SWZ(r) ((((r) + ((r) >> 2))) & 3)          // legacy swizzle (head_fused)
#define SW4(row, c) ((c) ^ (((row) >> 1) & 3))     // slot swizzle
#define RSCALE 2048.0f
#define INV_RSCALE (1.0f / 2048.0f)

#define GLOBAL_AS __attribute__((address_space(1)))
#define LDS_AS    __attribute__((address_space(3)))

__device__ __forceinline__ void gload16(const void* g, void* lds) {
    __builtin_amdgcn_global_load_lds((const GLOBAL_AS void*)g, (LDS_AS void*)lds, 16, 0, 0);
}

__device__ __forceinline__ float rd_any(const void* p, size_t i, int flag) {
    return flag ? (float)((const __hip_bfloat16*)p)[i] : ((const float*)p)[i];
}

__device__ __forceinline__ void wg_bar() {
    asm volatile("" ::: "memory");
    __builtin_amdgcn_s_barrier();
    asm volatile("" ::: "memory");
}
#define LGKMN(n) do { asm volatile("s_waitcnt lgkmcnt(" #n ")" ::: "memory"); \
                      __builtin_amdgcn_sched_barrier(0); } while (0)
#define VMW(n)  asm volatile("s_waitcnt vmcnt(" #n ")" ::: "memory")
#define SB0()   __builtin_amdgcn_sched_barrier(0)
#define MFMA16(a,b,c) __builtin_amdgcn_mfma_f32_16x16x32_f16((a),(b),(c),0,0,0)

// ---------------------------------------------------------------------------
__global__ void detect_dtype(const unsigned int* __restrict__ x, int* __restrict__ flag) {
    __shared__ int cnt;
    if (threadIdx.x == 0) cnt = 0;
    __syncthreads();
    int local = 0;
#pragma unroll
    for (int i = 0; i < 4; ++i) {
        unsigned int w = x[threadIdx.x * 4 + i];
        unsigned int e = (w >> 7) & 0xFFu;
        if (e >= 96u && e <= 144u) local++;
    }
    atomicAdd(&cnt, local);
    __syncthreads();
    if (threadIdx.x == 0) *flag = (cnt >= 600) ? 1 : 0;   // 1 = bf16 inputs
}

// ---------------------------------------------------------------------------
// prep_all: fused prep.  Sections (by blockIdx.x):
//   [0,8192)      split_x        (x -> xh, xl)   vectorized (R16)
//   [8192,8704)   split_w1t      (W1_1 -> whT, wlT)   32x16 tiles
//   [8704,9216)   transpose W2_1 -> W2Tf  [2048][1024] 32x16 tiles
//   [9216,9472)   transpose W2_2 -> W22Tf [256][4096]   4x64 tiles
//   [9472,9504)   split_w12t     (W1_2 -> w12h, w12l)  32 tiles
// ---------------------------------------------------------------------------
__global__ void prep_all(
    const void* __restrict__ x, const void* __restrict__ W1_1,
    const void* __restrict__ W2_1, const void* __restrict__ W2_2,
    const void* __restrict__ W1_2,
    _Float16* __restrict__ xh, _Float16* __restrict__ xl,
    _Float16* __restrict__ whT, _Float16* __restrict__ wlT,
    _Float16* __restrict__ W2Tf, _Float16* __restrict__ W22Tf,
    _Float16* __restrict__ w12h, _Float16* __restrict__ w12l,
    const int* __restrict__ flagp)
{
    __shared__ __align__(16) float tile[64][65];
    int flag = *flagp;
    int bid = blockIdx.x, t = threadIdx.x;
    int tx = t & 63, ty = t >> 6;

    if (bid < 8192) {                       // split_x, vectorized
        size_t i = ((size_t)bid * 256 + t) * 4;
        float a0, a1, a2, a3;
        if (flag) {
            u16x4 u = *(const u16x4*)((const unsigned short*)x + i);
            a0 = __uint_as_float(((unsigned)u[0]) << 16);
            a1 = __uint_as_float(((unsigned)u[1]) << 16);
            a2 = __uint_as_float(((unsigned)u[2]) << 16);
            a3 = __uint_as_float(((unsigned)u[3]) << 16);
        } else {
            f32x4 f = *(const f32x4*)((const float*)x + i);
            a0 = f[0]; a1 = f[1]; a2 = f[2]; a3 = f[3];
        }
        f16x4 hv, lv;
        _Float16 h0 = (_Float16)a0; hv[0] = h0; lv[0] = (_Float16)((a0 - (float)h0) * RSCALE);
        _Float16 h1 = (_Float16)a1; hv[1] = h1; lv[1] = (_Float16)((a1 - (float)h1) * RSCALE);
        _Float16 h2 = (_Float16)a2; hv[2] = h2; lv[2] = (_Float16)((a2 - (float)h2) * RSCALE);
        _Float16 h3 = (_Float16)a3; hv[3] = h3; lv[3] = (_Float16)((a3 - (float)h3) * RSCALE);
        *(f16x4*)(xh + i) = hv;
        *(f16x4*)(xl + i) = lv;
        return;
    }

    if (bid < 8704) {                       // split_w1t: [1024][2048] -> T
        int b = bid - 8192;
        int c0 = (b & 31) * 64, r0 = (b >> 5) * 64;
#pragma unroll
        for (int i = 0; i < 16; ++i) {
            int r = ty + i * 4;
            tile[r][tx] = rd_any(W1_1, (size_t)(r0 + r) * 2048 + c0 + tx, flag);
        }
        __syncthreads();
#pragma unroll
        for (int i = 0; i < 16; ++i) {
            int r = ty + i * 4;
            size_t o = (size_t)(c0 + r) * 1024 + r0 + tx;
            float a = tile[tx][r];
            _Float16 h = (_Float16)a;
            whT[o] = h;
            wlT[o] = (_Float16)((a - (float)h) * RSCALE);
        }
        return;
    }

    if (bid < 9216) {                       // W2_1 [1024][2048] -> W2Tf
        int b = bid - 8704;
        int c0 = (b & 31) * 64, r0 = (b >> 5) * 64;
#pragma unroll
        for (int i = 0; i < 16; ++i) {
            int r = ty + i * 4;
            tile[r][tx] = rd_any(W2_1, (size_t)(r0 + r) * 2048 + c0 + tx, flag);
        }
        __syncthreads();
#pragma unroll
        for (int i = 0; i < 16; ++i) {
            int r = ty + i * 4;
            W2Tf[(size_t)(c0 + r) * 1024 + r0 + tx] = (_Float16)tile[tx][r];
        }
        return;
    }

    if (bid < 9472) {                       // W2_2 [4096][256] -> W22Tf
        int b = bid - 9216;
        int c0 = (b & 3) * 64, r0 = (b >> 2) * 64;
#pragma unroll
        for (int i = 0; i < 16; ++i) {
            int r = ty + i * 4;
            tile[r][tx] = rd_any(W2_2, (size_t)(r0 + r) * 256 + c0 + tx, flag);
        }
        __syncthreads();
#pragma unroll
        for (int i = 0; i < 16; ++i) {
            int r = ty + i * 4;
            W22Tf[(size_t)(c0 + r) * 4096 + r0 + tx] = (_Float16)tile[tx][r];
        }
        return;
    }

    {                                       // split_w12t: [2048][64] -> T
        int b = bid - 9472;
        int r0 = b * 64;
#pragma unroll
        for (int i = 0; i < 16; ++i) {
            int r = ty + i * 4;
            tile[r][tx] = rd_any(W1_2, (size_t)(r0 + r) * 64 + tx, flag);
        }
        __syncthreads();
#pragma unroll
        for (int i = 0; i < 16; ++i) {
            int r = ty + i * 4;
            size_t o = (size_t)r * 2048 + r0 + tx;
            float a = tile[tx][r];
            _Float16 h = (_Float16)a;
            w12h[o] = h;
            w12l[o] = (_Float16)((a - (float)h) * RSCALE);
        }
    }
}

// ---------------------------------------------------------------------------
// h12_gemm8: slot-ring, ONE barrier/slot.  h1 branch (R16): MFMA split by
// A-rt; steady per-slot issue order (wave-local):
//   [outstanding: BA4, Alow4, BB4]  stage6  rdAhigh4  LGKMN(4)
//   cluster1 rt01xct0-3 (24)  LGKMN(0)  cluster2a rt23xct01 (12)
//   VMW  bar  rdBA4 rdAlow4  SB0  cluster2b rt23xct23 (12)  rdBB4
// Only rdBB (4 reads) is exposed; was 12 in R13.
// ---------------------------------------------------------------------------
__global__ __launch_bounds__(512, 2) void h12_gemm8(
    const _Float16* __restrict__ xh, const _Float16* __restrict__ xl,
    const _Float16* __restrict__ whT, const _Float16* __restrict__ wlT,
    const void* __restrict__ b11,
    const _Float16* __restrict__ W2Tf, const void* __restrict__ b21,
    _Float16* __restrict__ h1h, _Float16* __restrict__ h1l,
    _Float16* __restrict__ h2b,
    const int* __restrict__ flagp)
{
    __shared__ __align__(16) char smem[147456];
    int flag = *flagp;
    int t = threadIdx.x, w = t >> 6, lane = t & 63;
    int ml = lane & 15, q = lane >> 4, rq = q * 4;

    int xcd = blockIdx.x & 7, rblk = blockIdx.x >> 3;   // 8 XCDs x 96

    if (rblk < 64) {
        // ================= h1: 3-term, BM=256 BN=128, ring-3 =================
        int lb = xcd * 64 + rblk;
        int mt = lb >> 4, nt = lb & 15;
        int i0 = mt * 256, j0 = nt * 128;
        int wr = w & 3, wc = w >> 2;                    // 4 x 2 waves

        f32x4 acc1[4][4], acc2[4][4];
#pragma unroll
        for (int a = 0; a < 4; ++a)
#pragma unroll
            for (int b = 0; b < 4; ++b) {
                acc1[a][b] = (f32x4){0.f, 0.f, 0.f, 0.f};
                acc2[a][b] = (f32x4){0.f, 0.f, 0.f, 0.f};
            }

        // persistent frag regs: full A planes + full B (same 64 VGPR as R13)
        f16x8 ah[4], al[4], bh[4], bl[4];

        // slot layout: Ah @0 (16K), Al @16384 (16K), Bh @32768 (8K), Bl @40960 (8K)
        auto stage = [&](char* bp, int kt, int g) {
            if (g < 4) {                                // g0,1: Ah  g2,3: Al
                int ci = ((g & 1) << 9) + t;            // 0..1023
                int row = ci >> 2;
                int c = SW4(row, ci & 3);
                const _Float16* src = (g < 2) ? xh : xl;
                gload16(src + (size_t)(i0 + row) * 1024 + kt + c * 8,
                        bp + ((g < 2) ? 0 : 16384) + ci * 16);
            } else {                                    // g4: Bh  g5: Bl
                int ci = t;                             // 0..511
                int row = ci >> 2;
                int c = SW4(row, ci & 3);
                const _Float16* src = (g == 4) ? whT : wlT;
                gload16(src + (size_t)(j0 + row) * 1024 + kt + c * 8,
                        bp + ((g == 4) ? 32768 : 40960) + ci * 16);
            }
        };
        auto rdBA = [&](char* bp) {                     // 4 reads: B ct0,1
#pragma unroll
            for (int ct = 0; ct < 2; ++ct) {
                int row = wc * 64 + ct * 16 + ml;
                int off = row * 64 + (SW4(row, q) << 4);
                bh[ct] = *(const f16x8*)(bp + 32768 + off);
                bl[ct] = *(const f16x8*)(bp + 40960 + off);
            }
        };
        auto rdBB = [&](char* bp) {                     // 4 reads: B ct2,3
#pragma unroll
            for (int ct = 2; ct < 4; ++ct) {
                int row = wc * 64 + ct * 16 + ml;
                int off = row * 64 + (SW4(row, q) << 4);
                bh[ct] = *(const f16x8*)(bp + 32768 + off);
                bl[ct] = *(const f16x8*)(bp + 40960 + off);
            }
        };
        auto rdAlow = [&](char* bp) {                   // 4 reads: A rt0,1
#pragma unroll
            for (int rt = 0; rt < 2; ++rt) {
                int row = wr * 64 + rt * 16 + ml;
                int off = row * 64 + (SW4(row, q) << 4);
                ah[rt] = *(const f16x8*)(bp + off);
                al[rt] = *(const f16x8*)(bp + 16384 + off);
            }
        };
        auto rdAhigh = [&](char* bp) {                  // 4 reads: A rt2,3
#pragma unroll
            for (int rt = 2; rt < 4; ++rt) {
                int row = wr * 64 + rt * 16 + ml;
                int off = row * 64 + (SW4(row, q) << 4);
                ah[rt] = *(const f16x8*)(bp + off);
                al[rt] = *(const f16x8*)(bp + 16384 + off);
            }
        };

        // prologue: stage slots 0,1; issue slot-0 reads in invariant order
#pragma unroll
        for (int g = 0; g < 6; ++g) stage(smem, 0, g);
#pragma unroll
        for (int g = 0; g < 6; ++g) stage(smem + 49152, 32, g);
        VMW(6);                                         // slot0 landed
        wg_bar();
        rdBA(smem);   SB0();
        rdAlow(smem); SB0();
        rdBB(smem);   SB0();

        int cur = 0;
        for (int s = 0; s < 32; ++s) {
            char* bpc = smem + cur * 49152;
            char* bpn = smem + ((cur + 1 == 3) ? 0 : cur + 1) * 49152;
            int cur2 = cur + 2; if (cur2 >= 3) cur2 -= 3;
            char* bp2 = smem + cur2 * 49152;
            int kt2 = (s + 2) * 32;
            bool st = (s < 30), rd = (s < 31);

            if (st) {
#pragma unroll
                for (int g = 0; g < 6; ++g) stage(bp2, kt2, g);
            }
            rdAhigh(bpc);                               // buf s, 4 reads
            LGKMN(4);                                   // BA+Alow+BB done
            __builtin_amdgcn_s_setprio(1);
#pragma unroll
            for (int rt = 0; rt < 2; ++rt)              // cluster1: 24 MFMA
#pragma unroll
                for (int ct = 0; ct < 4; ++ct) {
                    acc1[rt][ct] = MFMA16(ah[rt], bh[ct], acc1[rt][ct]);
                    acc2[rt][ct] = MFMA16(ah[rt], bl[ct], acc2[rt][ct]);
                    acc2[rt][ct] = MFMA16(al[rt], bh[ct], acc2[rt][ct]);
                }
            __builtin_amdgcn_s_setprio(0);
            LGKMN(0);                                   // Ahigh done
            __builtin_amdgcn_s_setprio(1);
#pragma unroll
            for (int rt = 2; rt < 4; ++rt)              // cluster2a: 12 MFMA
#pragma unroll
                for (int ct = 0; ct < 2; ++ct) {
                    acc1[rt][ct] = MFMA16(ah[rt], bh[ct], acc1[rt][ct]);
                    acc2[rt][ct] = MFMA16(ah[rt], bl[ct], acc2[rt][ct]);
                    acc2[rt][ct] = MFMA16(al[rt], bh[ct], acc2[rt][ct]);
                }
            __builtin_amdgcn_s_setprio(0);
            if (st) { VMW(6); } else { VMW(0); }        // buf s+1 landed
            wg_bar();
            if (rd) { rdBA(bpn); rdAlow(bpn); }         // 8 reads, hidden
            SB0();
            __builtin_amdgcn_s_setprio(1);
#pragma unroll
            for (int rt = 2; rt < 4; ++rt)              // cluster2b: 12 MFMA
#pragma unroll
                for (int ct = 2; ct < 4; ++ct) {
                    acc1[rt][ct] = MFMA16(ah[rt], bh[ct], acc1[rt][ct]);
                    acc2[rt][ct] = MFMA16(ah[rt], bl[ct], acc2[rt][ct]);
                    acc2[rt][ct] = MFMA16(al[rt], bh[ct], acc2[rt][ct]);
                }
            __builtin_amdgcn_s_setprio(0);
            if (rd) rdBB(bpn);                          // 4 reads, exposed
            SB0();
            cur = cur + 1; if (cur == 3) cur = 0;
        }

        // ---- epilogue: bias + relu, 2-plane split out via LDS restage ----
#pragma unroll
        for (int ct = 0; ct < 4; ++ct) {
            float bv = rd_any(b11, j0 + wc * 64 + ct * 16 + ml, flag);
#pragma unroll
            for (int rt = 0; rt < 4; ++rt)
#pragma unroll
                for (int rr = 0; rr < 4; ++rr) {
                    float v = acc1[rt][ct][rr] + acc2[rt][ct][rr] * INV_RSCALE + bv;
                    acc1[rt][ct][rr] = v > 0.f ? v : 0.f;
                }
        }
        _Float16* C = (_Float16*)smem;
#pragma unroll
        for (int p = 0; p < 2; ++p) {
            __syncthreads();
#pragma unroll
            for (int rt = 0; rt < 4; ++rt)
#pragma unroll
                for (int ct = 0; ct < 4; ++ct)
#pragma unroll
                    for (int rr = 0; rr < 4; ++rr) {
                        float v = acc1[rt][ct][rr];
                        _Float16 h = (_Float16)v;
                        _Float16 outv = (p == 0) ? h
                                      : (_Float16)((v - (float)h) * RSCALE);
                        int rl = wr * 64 + rt * 16 + rq + rr;
                        int cl = wc * 64 + ct * 16 + ml;
                        C[rl * 136 + cl] = outv;
                    }
            __syncthreads();
            _Float16* dst = (p == 0) ? h1h : h1l;
#pragma unroll
            for (int i = 0; i < 8; ++i) {
                int c = i * 512 + t;
                int row = c >> 4, c8 = (c & 15) * 8;
                *(f16x8*)(dst + (size_t)(i0 + row) * 2048 + j0 + c8) =
                    *(const f16x8*)(C + row * 136 + c8);
            }
        }
    } else {
        // ================= h2: 1-term, BM=256 BN=256, ring-4 =================
        int lb = xcd * 32 + (rblk - 64);
        int mt = lb >> 3, nt = lb & 7;
        int i0 = mt * 256, j0 = nt * 256;
        int wr = w & 1, wc = w >> 1;                    // 2 x 4 waves

        f32x4 acc[8][4];
#pragma unroll
        for (int a = 0; a < 8; ++a)
#pragma unroll
            for (int b = 0; b < 4; ++b) acc[a][b] = (f32x4){0.f, 0.f, 0.f, 0.f};

        // persistent frags: af rt0-3, af rt4-7, bf double-buffer (static names)
        f16x8 af0[4], af4[4], bfa[4], bfb[4];

        // slot layout: A @0 (16K), B @16384 (16K)
        auto stage = [&](char* bp, int kt, int g) {
            int ci = ((g & 1) << 9) + t;                // 0..1023
            int row = ci >> 2;
            int c = SW4(row, ci & 3);
            if (g < 2)
                gload16(xh + (size_t)(i0 + row) * 1024 + kt + c * 8,
                        bp + ci * 16);
            else
                gload16(W2Tf + (size_t)(j0 + row) * 1024 + kt + c * 8,
                        bp + 16384 + ci * 16);
        };
        auto rdBF = [&](char* bp, f16x8* dst) {         // 4 reads: all B ct
#pragma unroll
            for (int ct = 0; ct < 4; ++ct) {
                int row = wc * 64 + ct * 16 + ml;
                int off = row * 64 + (SW4(row, q) << 4);
                dst[ct] = *(const f16x8*)(bp + 16384 + off);
            }
        };
        auto rdA0 = [&](char* bp) {                     // 4 reads: rt0-3
#pragma unroll
            for (int rt = 0; rt < 4; ++rt) {
                int row = wr * 128 + rt * 16 + ml;
                int off = row * 64 + (SW4(row, q) << 4);
                af0[rt] = *(const f16x8*)(bp + off);
            }
        };
        auto rdA4 = [&](char* bp) {                     // 4 reads: rt4-7
#pragma unroll
            for (int rt = 0; rt < 4; ++rt) {
                int row = wr * 128 + (rt + 4) * 16 + ml;
                int off = row * 64 + (SW4(row, q) << 4);
                af4[rt] = *(const f16x8*)(bp + off);
            }
        };

#pragma unroll
        for (int g = 0; g < 4; ++g) stage(smem, 0, g);
#pragma unroll
        for (int g = 0; g < 4; ++g) stage(smem + 32768, 32, g);
        VMW(4);
        wg_bar();
        rdBF(smem, bfa); SB0();
        rdA0(smem);      SB0();
        rdA4(smem);      SB0();

        int cur = 0;
        // one slot body; BFC = current bf regs, BFN = next bf regs
        auto body = [&](int s, f16x8* BFC, f16x8* BFN) {
            char* bpn = smem + ((cur + 1) & 3) * 32768;
            char* bp2 = smem + ((cur + 2) & 3) * 32768;
            int kt2 = (s + 2) * 32;
            bool st = (s < 30), rd = (s < 31);

            if (st) {
#pragma unroll
                for (int g = 0; g < 4; ++g) stage(bp2, kt2, g);
            }
            LGKMN(4);                                   // BFC, af0 ready
            __builtin_amdgcn_s_setprio(1);
#pragma unroll
            for (int rt = 0; rt < 4; ++rt)
#pragma unroll
                for (int ct = 0; ct < 4; ++ct)
                    acc[rt][ct] = MFMA16(af0[rt], BFC[ct], acc[rt][ct]);
            __builtin_amdgcn_s_setprio(0);
            LGKMN(0);                                   // af4 ready
            if (st) { VMW(4); } else { VMW(0); }
            wg_bar();
            if (rd) { rdBF(bpn, BFN); rdA0(bpn); }      // first-8 of s+1
            SB0();
            __builtin_amdgcn_s_setprio(1);
#pragma unroll
            for (int rt = 0; rt < 4; ++rt)
#pragma unroll
                for (int ct = 0; ct < 4; ++ct)
                    acc[rt + 4][ct] = MFMA16(af4[rt], BFC[ct], acc[rt + 4][ct]);
            __builtin_amdgcn_s_setprio(0);
            if (rd) rdA4(bpn);                          // last-4 of s+1
            cur = (cur + 1) & 3;
        };

        for (int k = 0; k < 16; ++k) {
            body(2 * k,     bfa, bfb);
            body(2 * k + 1, bfb, bfa);
        }

        // ---- epilogue: bias + relu, f16 out via LDS restage ----
        _Float16* C = (_Float16*)smem;
        __syncthreads();
#pragma unroll
        for (int ct = 0; ct < 4; ++ct) {
            float bv = rd_any(b21, j0 + wc * 64 + ct * 16 + ml, flag);
#pragma unroll
            for (int rt = 0; rt < 8; ++rt)
#pragma unroll
                for (int rr = 0; rr < 4; ++rr) {
                    float v = acc[rt][ct][rr] + bv;
                    v = v > 0.f ? v : 0.f;
                    int rl = wr * 128 + rt * 16 + rq + rr;
                    int cl = wc * 64 + ct * 16 + ml;
                    C[rl * 264 + cl] = (_Float16)v;
                }
        }
        __syncthreads();
#pragma unroll
        for (int i = 0; i < 16; ++i) {
            int c = i * 512 + t;
            int row = c >> 5, c8 = (c & 31) * 8;
            *(f16x8*)(h2b + (size_t)(i0 + row) * 2048 + j0 + c8) =
                *(const f16x8*)(C + row * 264 + c8);
        }
    }
}

// ---------------------------------------------------------------------------
// head_fused (R13 version): blocks [0,512) = l2_gemm (partials);
// [512,1024) = l1_mfma (L1 softmax + argmax).  16KB LDS.
// ---------------------------------------------------------------------------
__global__ __launch_bounds__(256, 2) void head_fused(
    const _Float16* __restrict__ h1h, const _Float16* __restrict__ h1l,
    const _Float16* __restrict__ h2b, const _Float16* __restrict__ W22T,
    float* __restrict__ partials,
    const _Float16* __restrict__ w12h, const _Float16* __restrict__ w12l,
    const void* __restrict__ b12, float* __restrict__ L1out,
    int* __restrict__ parent, const int* __restrict__ flagp)
{
    constexpr int BK = 32;
    __shared__ __align__(16) char smem[16384];
    int flag = *flagp;
    int t = threadIdx.x, w = t >> 6, lane = t & 63;
    int ml = lane & 15, q = lane >> 4;

    if (blockIdx.x < 512) {
        // ----- l2_gemm -----
        _Float16* As = (_Float16*)smem;
        _Float16* Bs = (_Float16*)(smem + 8192);
        int bid = blockIdx.x;
        int g = bid & 7, s = bid >> 3;
        int mt = g * 8 + (s & 7);
        int rest = s >> 3;
        int nt = rest & 1, kc = rest >> 1;
        int i0 = mt * 128, j0 = nt * 128;
        const _Float16* Abase = (kc < 2) ? h1h : h2b;
        int kof = (kc & 1) * 1024;
        int wr = w & 1, wcb = w >> 1;

        f32x4 acc[4][4];
#pragma unroll
        for (int a = 0; a < 4; ++a)
#pragma unroll
            for (int b = 0; b < 4; ++b) acc[a][b] = (f32x4){0.f, 0.f, 0.f, 0.f};

        for (int kt = 0; kt < 1024; kt += BK) {
            __syncthreads();
#pragma unroll
            for (int qq = 0; qq < 2; ++qq) {
                int c = qq * 256 + t;
                int row = c >> 2;
                int gc = (c & 3) ^ SWZ(row);
                gload16(Abase + (size_t)(i0 + row) * 2048 + kof + kt + gc * 8, (char*)As + c * 16);
                gload16(W22T + (size_t)(j0 + row) * 4096 + kc * 1024 + kt + gc * 8, (char*)Bs + c * 16);
            }
            __syncthreads();
            f16x8 af[4], bf[4];
#pragma unroll
            for (int rt = 0; rt < 4; ++rt) {
                int row = wr * 64 + rt * 16 + ml;
                af[rt] = *(const f16x8*)(As + row * 32 + ((q ^ SWZ(row)) << 3));
            }
#pragma unroll
            for (int ct = 0; ct < 4; ++ct) {
                int row = wcb * 64 + ct * 16 + ml;
                bf[ct] = *(const f16x8*)(Bs + row * 32 + ((q ^ SWZ(row)) << 3));
            }
#pragma unroll
            for (int rt = 0; rt < 4; ++rt)
#pragma unroll
                for (int ct = 0; ct < 4; ++ct)
                    acc[rt][ct] = __builtin_amdgcn_mfma_f32_16x16x32_f16(
                        af[rt], bf[ct], acc[rt][ct], 0, 0, 0);
        }

        float* out = partials + (size_t)kc * 8192 * 256;
        int rq = (lane >> 4) * 4;
#pragma unroll
        for (int ct = 0; ct < 4; ++ct) {
            int nl = j0 + wcb * 64 + ct * 16 + ml;
#pragma unroll
            for (int rt = 0; rt < 4; ++rt) {
                int mbase = i0 + wr * 64 + rt * 16 + rq;
#pragma unroll
                for (int r = 0; r < 4; ++r)
                    out[(size_t)(mbase + r) * 256 + nl] = acc[rt][ct][r];
            }
        }
    } else {
        // ----- l1_mfma: 16 rows/block, 4-wave K-split, 3-term -----
        float* red = (float*)smem;          // [3][4][256] floats = 12 KB
        int r0 = (blockIdx.x - 512) * 16;
        int kq = (lane >> 4) * 8;

        f32x4 acch[4], accx[4];
#pragma unroll
        for (int ct = 0; ct < 4; ++ct) {
            acch[ct] = (f32x4){0.f, 0.f, 0.f, 0.f};
            accx[ct] = (f32x4){0.f, 0.f, 0.f, 0.f};
        }

        size_t aoff = (size_t)(r0 + ml) * 2048 + w * 512 + kq;
        const _Float16* Ah = h1h + aoff;
        const _Float16* Al = h1l + aoff;
        size_t boff[4];
#pragma unroll
        for (int ct = 0; ct < 4; ++ct)
            boff[ct] = (size_t)(ct * 16 + ml) * 2048 + w * 512 + kq;

        f16x8 ah = *(const f16x8*)(Ah), al = *(const f16x8*)(Al);
        f16x8 bh[4], bl[4];
#pragma unroll
        for (int ct = 0; ct < 4; ++ct) {
            bh[ct] = *(const f16x8*)(w12h + boff[ct]);
            bl[ct] = *(const f16x8*)(w12l + boff[ct]);
        }

        for (int kt = 0; kt < 512; kt += 32) {
            int nk = (kt + 32) & 511;
            f16x8 nah = *(const f16x8*)(Ah + nk);
            f16x8 nal = *(const f16x8*)(Al + nk);
            f16x8 nbh[4], nbl[4];
#pragma unroll
            for (int ct = 0; ct < 4; ++ct) {
                nbh[ct] = *(const f16x8*)(w12h + boff[ct] + nk);
                nbl[ct] = *(const f16x8*)(w12l + boff[ct] + nk);
            }
#pragma unroll
            for (int ct = 0; ct < 4; ++ct) {
                acch[ct] = __builtin_amdgcn_mfma_f32_16x16x32_f16(ah, bh[ct], acch[ct], 0, 0, 0);
                accx[ct] = __builtin_amdgcn_mfma_f32_16x16x32_f16(ah, bl[ct], accx[ct], 0, 0, 0);
                accx[ct] = __builtin_amdgcn_mfma_f32_16x16x32_f16(al, bh[ct], accx[ct], 0, 0, 0);
            }
            ah = nah; al = nal;
#pragma unroll
            for (int ct = 0; ct < 4; ++ct) { bh[ct] = nbh[ct]; bl[ct] = nbl[ct]; }
        }

        f32x4 acc[4];
#pragma unroll
        for (int ct = 0; ct < 4; ++ct)
#pragma unroll
            for (int i = 0; i < 4; ++i)
                acc[ct][i] = acch[ct][i] + accx[ct][i] * INV_RSCALE;

        if (w > 0) {
#pragma unroll
            for (int ct = 0; ct < 4; ++ct)
#pragma unroll
                for (int i = 0; i < 4; ++i)
                    red[((w - 1) * 4 + ct) * 256 + lane * 4 + i] = acc[ct][i];
        }
        __syncthreads();
        if (w != 0) return;

#pragma unroll
        for (int wv = 0; wv < 3; ++wv)
#pragma unroll
            for (int ct = 0; ct < 4; ++ct)
#pragma unroll
                for (int i = 0; i < 4; ++i)
                    acc[ct][i] += red[(wv * 4 + ct) * 256 + lane * 4 + i];

        int rq = (lane >> 4) * 4;
        float vals[4][4];
        float vmax[4] = {-1e30f, -1e30f, -1e30f, -1e30f};
        int vidx[4] = {1 << 30, 1 << 30, 1 << 30, 1 << 30};
#pragma unroll
        for (int ct = 0; ct < 4; ++ct) {
            int col = ct * 16 + ml;
            float bv = rd_any(b12, col, flag);
#pragma unroll
            for (int r = 0; r < 4; ++r) {
                float v = acc[ct][r] + bv;
                v = v > 0.f ? v : 0.f;
                vals[ct][r] = v;
                if (v > vmax[r] || (v == vmax[r] && col < vidx[r])) { vmax[r] = v; vidx[r] = col; }
            }
        }
#pragma unroll
        for (int d = 1; d < 16; d <<= 1) {
#pragma unroll
            for (int r = 0; r < 4; ++r) {
                float om = __shfl_xor(vmax[r], d);
                int oi = __shfl_xor(vidx[r], d);
                if (om > vmax[r] || (om == vmax[r] && oi < vidx[r])) { vmax[r] = om; vidx[r] = oi; }
            }
        }
        float vsum[4] = {0.f, 0.f, 0.f, 0.f};
#pragma unroll
        for (int ct = 0; ct < 4; ++ct)
#pragma unroll
            for (int r = 0; r < 4; ++r) {
                float e = __expf(vals[ct][r] - vmax[r]);
                vals[ct][r] = e;
                vsum[r] += e;
            }
#pragma unroll
        for (int d = 1; d < 16; d <<= 1)
#pragma unroll
            for (int r = 0; r < 4; ++r) vsum[r] += __shfl_xor(vsum[r], d);

#pragma unroll
        for (int r = 0; r < 4; ++r) {
            float inv = 1.0f / vsum[r];
            int grow = r0 + rq + r;
#pragma unroll
            for (int ct = 0; ct < 4; ++ct)
                L1out[(size_t)grow * 64 + ct * 16 + ml] = vals[ct][r] * inv;
            if (ml == 0) parent[grow] = vidx[r];
        }
    }
}

// ---------------------------------------------------------------------------
__global__ __launch_bounds__(256, 2) void l2_softmax(
    const float* __restrict__ partials, const void* __restrict__ b22,
    const int* __restrict__ child_parent, const int* __restrict__ parent,
    float* __restrict__ L2out, const int* __restrict__ flagp)
{
    int flag = *flagp;
    int t = threadIdx.x, w = t >> 6, lane = t & 63;
    int row = blockIdx.x * 4 + w;
    int c4 = lane * 4;

    float v[4] = {0.f, 0.f, 0.f, 0.f};
#pragma unroll
    for (int kc = 0; kc < 4; ++kc) {
        float4 pv = *(const float4*)(partials + ((size_t)kc * 8192 + row) * 256 + c4);
        v[0] += pv.x; v[1] += pv.y; v[2] += pv.z; v[3] += pv.w;
    }
    int par = parent[row];
#pragma unroll
    for (int j = 0; j < 4; ++j) {
        float x = v[j] + rd_any(b22, c4 + j, flag);
        x = x > 0.f ? x : 0.f;
        if (child_parent[c4 + j] != par) x += MASK_VALUE;
        v[j] = x;
    }
    float m = fmaxf(fmaxf(v[0], v[1]), fmaxf(v[2], v[3]));
#pragma unroll
    for (int d = 1; d < 64; d <<= 1) m = fmaxf(m, __shfl_xor(m, d));
    float sum = 0.f;
#pragma unroll
    for (int j = 0; j < 4; ++j) { v[j] = __expf(v[j] - m); sum += v[j]; }
#pragma unroll
    for (int d = 1; d < 64; d <<= 1) sum += __shfl_xor(sum, d);
    float inv = 1.0f / sum;
    float4 o = {v[0] * inv, v[1] * inv, v[2] * inv, v[3] * inv};
    *(float4*)(L2out + (size_t)row * 256 + c4) = o;
}

// ---------------------------------------------------------------------------
extern "C" void kernel_launch(void* const* d_in, const int* in_sizes, int n_in,
                              void* d_out, int out_size, void* d_ws, size_t ws_size,
                              hipStream_t stream) {
    (void)in_sizes; (void)n_in; (void)out_size; (void)ws_size;

    const void* x    = d_in[0];
    const void* W1_1 = d_in[1];
    const void* b1_1 = d_in[2];
    const void* W1_2 = d_in[3];
    const void* b1_2 = d_in[4];
    const void* W2_1 = d_in[5];
    const void* b2_1 = d_in[6];
    const void* W2_2 = d_in[7];
    const void* b2_2 = d_in[8];
    const int* child_parent = (const int*)d_in[9];

    // ws layout, 183 MB total:
    char* p = (char*)d_ws;
    _Float16* xh    = (_Float16*)(p);                 // 16 MB [8192][1024]
    _Float16* xl    = (_Float16*)(p + 16777216);      // 16 MB
    _Float16* whT   = (_Float16*)(p + 33554432);      //  4 MB [2048][1024]
    _Float16* wlT   = (_Float16*)(p + 37748736);      //  4 MB
    _Float16* h1h   = (_Float16*)(p + 41943040);      // 32 MB [8192][2048]
    _Float16* h1l   = (_Float16*)(p + 75497472);      // 32 MB
    _Float16* h2b   = (_Float16*)(p + 109051904);     // 32 MB [8192][2048]
    _Float16* W2Tf  = (_Float16*)(p + 142606336);     //  4 MB [2048][1024]
    _Float16* W22Tf = (_Float16*)(p + 146800640);     //  2 MB [256][4096]
    _Float16* w12h  = (_Float16*)(p + 148897792);     // 256 KB [64][2048]
    _Float16* w12l  = (_Float16*)(p + 149159936);     // 256 KB
    float* partials = (float*)(p + 149422080);        // 32 MB [4][8192][256]
    int* parent     = (int*)(p + 182976512);          // 32 KB
    int* flag       = (int*)(p + 183009280);

    float* L1out = (float*)d_out;
    float* L2out = L1out + (size_t)8192 * 64;

    hipLaunchKernelGGL(detect_dtype, dim3(1), dim3(256), 0, stream,
                       (const unsigned int*)x, flag);
    hipLaunchKernelGGL(prep_all, dim3(9504), dim3(256), 0, stream,
                       x, W1_1, W2_1, W2_2, W1_2,
                       xh, xl, whT, wlT, W2Tf, W22Tf, w12h, w12l, flag);
    hipLaunchKernelGGL(h12_gemm8, dim3(768), dim3(512), 0, stream,
                       xh, xl, whT, wlT, b1_1, W2Tf, b2_1,
                       h1h, h1l, h2b, flag);
    hipLaunchKernelGGL(head_fused, dim3(1024), dim3(256), 0, stream,
                       h1h, h1l, h2b, W22Tf, partials,
                       w12h, w12l, b1_2, L1out, parent, flag);
    hipLaunchKernelGGL(l2_softmax, dim3(2048), dim3(256), 0, stream,
                       partials, b2_2, child_parent, parent, L2out, flag);
}